// Round 9
// baseline (255.698 us; speedup 1.0000x reference)
//
#include <hip/hip_runtime.h>
#include <math.h>
#include <float.h>

#define NPIX 2304   // 48*48
#define NPAD 2500   // 50*50
#define PLANE 573440  // 2560*224 padded [p][d] fp32 plane per batch
#define MARGIN 3e-4f

// ws layout in floats
#define OFF_QP     0u         // [2][2560][224] fp32
#define OFF_KP     1146880u   // [2][2560][224] fp32
#define OFF_PLANES 2293760u   // 4 bf16 planes x 2 batches, blocked+swizzled (see k_qk)
#define OFF_NK     4587520u   // [2][2500]
#define OFF_INVNK  4592520u   // [2][2304]
#define OFF_PVAL   4597128u   // [2][48][2304]
#define OFF_PSEC   4818312u   // [2][48][2304]
#define OFF_PIDX   5039496u   // int [2][48][2304]
#define OFF_IDX    5260680u   // int [2][2304]
#define OFF_FLAG   5265288u   // int [2][2304]
#define OFF_S      5269896u   // [2500][2500] single batch (two-pass)
#define OFF_SOFF   OFF_S      // int [2][9][2304] — aliases S (S dead by then)
#define PLANE_SH   573440     // shorts per (plane, batch)

typedef __attribute__((ext_vector_type(8))) short short8;
typedef __attribute__((ext_vector_type(4))) float f32x4;

__device__ __forceinline__ unsigned short bfhi(float f) {
    unsigned u = __float_as_uint(f);
    return (unsigned short)((u + 0x7FFFu + ((u >> 16) & 1u)) >> 16);
}

__device__ __forceinline__ void gload_lds16(const void* g, void* l) {
    __builtin_amdgcn_global_load_lds(
        (const __attribute__((address_space(1))) unsigned int*)g,
        (__attribute__((address_space(3))) unsigned int*)l, 16, 0, 0);
}

// ---- stage 1: q = W*x1, k = W*x2 -> fp32 [p][d] rows + bf16 hi/lo blocked planes ----
// bf16 plane layout (per plane, per batch): [panel P 0..19][chunk c 0..6][512 granules]
// granule = 8 bf16 = 16B; logical (row r 0..127, d-quad q 0..3) stored at granule
// G = r*4 + ((q + (r>>1)) & 3)  -> frag reads hit the 8-cycle LDS floor, and
// global_load_lds (linear lane*16B dest) reproduces this layout in LDS verbatim.
__global__ __launch_bounds__(256) void k_qk(const float* __restrict__ x1,
                                            const float* __restrict__ x2,
                                            const float* __restrict__ W,
                                            float* __restrict__ qp,
                                            float* __restrict__ kp,
                                            unsigned short* __restrict__ planes) {
    __shared__ float Ws[512];
    const int t = threadIdx.x;
    Ws[t] = W[t];
    Ws[t + 256] = W[t + 256];
    __syncthreads();
    const int img = blockIdx.x / 9;      // 0..49  (b*25 + a)
    const int chunk = blockIdx.x % 9;
    const int pix = chunk * 256 + t;     // 0..2303
    const int b = img / 25, a = img % 25;
    const int y = pix / 48, x = pix % 48;

    float q[8], k[8];
#pragma unroll
    for (int o = 0; o < 8; ++o) { q[o] = 0.f; k[o] = 0.f; }

    const float* p1 = x1 + (size_t)b * 64 * 57600 + a * 2304 + pix;
    const float* p2 = x2 + (size_t)b * 64 * 57600 + a * 2304 + pix;
    for (int c = 0; c < 64; ++c) {
        float v1 = p1[c * 57600];
        float v2 = p2[c * 57600];
#pragma unroll
        for (int o = 0; o < 8; ++o) {
            float w = Ws[o * 64 + c];
            q[o] = fmaf(w, v1, q[o]);
            k[o] = fmaf(w, v2, k[o]);
        }
    }
    const int p = (y + 1) * 50 + (x + 1);
    float* qd = qp + (size_t)b * PLANE + (size_t)p * 224 + a * 8;
    float* kd = kp + (size_t)b * PLANE + (size_t)p * 224 + a * 8;
    float4 q0 = { q[0], q[1], q[2], q[3] }, q1 = { q[4], q[5], q[6], q[7] };
    float4 k0 = { k[0], k[1], k[2], k[3] }, k1 = { k[4], k[5], k[6], k[7] };
    *(float4*)qd = q0; *(float4*)(qd + 4) = q1;
    *(float4*)kd = k0; *(float4*)(kd + 4) = k1;

    // bf16 hi/lo granules
    const int P = p >> 7, r = p & 127, cc = a >> 2, dq = a & 3;
    const int g = r * 4 + ((dq + (r >> 1)) & 3);
    const size_t goff = ((size_t)(P * 7 + cc) * 512 + g) * 8;
    short8 qh, ql, kh, kl;
#pragma unroll
    for (int o = 0; o < 8; ++o) {
        unsigned short h = bfhi(q[o]);
        qh[o] = (short)h;
        ql[o] = (short)bfhi(q[o] - __uint_as_float(((unsigned)h) << 16));
        h = bfhi(k[o]);
        kh[o] = (short)h;
        kl[o] = (short)bfhi(k[o] - __uint_as_float(((unsigned)h) << 16));
    }
    *(short8*)(planes + (size_t)(0 * 2 + b) * PLANE_SH + goff) = qh;
    *(short8*)(planes + (size_t)(1 * 2 + b) * PLANE_SH + goff) = ql;
    *(short8*)(planes + (size_t)(2 * 2 + b) * PLANE_SH + goff) = kh;
    *(short8*)(planes + (size_t)(3 * 2 + b) * PLANE_SH + goff) = kl;
}

// ---------------- per-position squared norms of k ----------------
__global__ void k_nk(const float* __restrict__ kp, float* __restrict__ nk) {
    int t = blockIdx.x * 256 + threadIdx.x;  // 0..4999
    if (t >= 2 * NPAD) return;
    int b = t / NPAD, p = t - b * NPAD;
    const float* src = kp + (size_t)b * PLANE + (size_t)p * 224;
    float s = 0.f;
    for (int d = 0; d < 200; d += 4) {
        float4 v = *(const float4*)(src + d);
        s = fmaf(v.x, v.x, s); s = fmaf(v.y, v.y, s);
        s = fmaf(v.z, v.z, s); s = fmaf(v.w, v.w, s);
    }
    nk[t] = s;
}

__global__ void k_invnk(const float* __restrict__ nk, float* __restrict__ invNk) {
    int t = blockIdx.x * 256 + threadIdx.x;  // 0..4607
    if (t >= 2 * NPIX) return;
    int b = t / NPIX, m = t - b * NPIX;
    int my = m / 48, mx = m % 48;
    const float* nb = nk + b * NPAD;
    float s = 0.f;
#pragma unroll
    for (int i = 0; i < 3; ++i)
#pragma unroll
        for (int j = 0; j < 3; ++j)
            s += nb[(my + i) * 50 + mx + j];
    invNk[t] = 1.0f / fmaxf(sqrtf(s), 1e-12f);
}

// ---- stage 2a: S ~= A^T B, 3-term bf16 split, global_load_lds staging, no in-loop cvt ----
__global__ __launch_bounds__(256, 2) void k_mfma2(const unsigned short* __restrict__ planes,
                                                  float* __restrict__ S, int b) {
    __shared__ unsigned short Abuf[2][4096];   // 128 rows x 32 d bf16, swizzled granules
    __shared__ unsigned short Bbuf[2][4096];
    const int t = threadIdx.x;
    // XCD-aware bijective swizzle (nwg = 400, %8 == 0)
    const int lin = blockIdx.y * gridDim.x + blockIdx.x;
    const int work = (lin & 7) * 50 + (lin >> 3);
    const int wy = work / 20, wx = work - (work / 20) * 20;

    const unsigned short* Ahi = planes + (size_t)(0 * 2 + b) * PLANE_SH;
    const unsigned short* Alo = planes + (size_t)(1 * 2 + b) * PLANE_SH;
    const unsigned short* Bhi = planes + (size_t)(2 * 2 + b) * PLANE_SH;
    const unsigned short* Blo = planes + (size_t)(3 * 2 + b) * PLANE_SH;

    const int p0 = wy * 128, r0 = wx * 128;
    const int wid = t >> 6, l = t & 63;
    const int lp = l & 15, dq = l >> 4;
    const int wqp = (wid >> 1) * 64, wqr = (wid & 1) * 64;

    // loop-invariant frag LDS offsets (shorts)
    int aoff[4], boff[4];
#pragma unroll
    for (int tr = 0; tr < 4; ++tr) {
        int rA = wqp + tr * 16 + lp;
        aoff[tr] = (rA * 4 + ((dq + (rA >> 1)) & 3)) * 8;
        int rB = wqr + tr * 16 + lp;
        boff[tr] = (rB * 4 + ((dq + (rB >> 1)) & 3)) * 8;
    }

    f32x4 acc[4][4];
#pragma unroll
    for (int i = 0; i < 4; ++i)
#pragma unroll
        for (int j = 0; j < 4; ++j) acc[i][j] = (f32x4){0.f, 0.f, 0.f, 0.f};

#define STAGE(buf, ks)                                                          \
    {                                                                           \
        const int term = (ks) / 7, c = (ks) - term * 7;                         \
        const unsigned short* gA = (term < 2 ? Ahi : Alo) + ((size_t)(wy * 7 + c) << 12); \
        const unsigned short* gB = (term != 1 ? Bhi : Blo) + ((size_t)(wx * 7 + c) << 12); \
        unsigned short* lA = &Abuf[buf][wid * 512];                             \
        unsigned short* lB = &Bbuf[buf][wid * 512];                             \
        gload_lds16(gA + t * 8, lA);                                            \
        gload_lds16(gA + 2048 + t * 8, lA + 2048);                              \
        gload_lds16(gB + t * 8, lB);                                            \
        gload_lds16(gB + 2048 + t * 8, lB + 2048);                              \
    }

    STAGE(0, 0);
    asm volatile("s_waitcnt vmcnt(0)" ::: "memory");
    __syncthreads();

    int cur = 0;
    for (int ks = 0; ks < 21; ++ks) {
        if (ks + 1 < 21) STAGE(cur ^ 1, ks + 1);
        {
            const unsigned short* Ab = &Abuf[cur][0];
            const unsigned short* Bb = &Bbuf[cur][0];
            short8 af[4], bfr[4];
#pragma unroll
            for (int tr = 0; tr < 4; ++tr) af[tr] = *(const short8*)(Ab + aoff[tr]);
#pragma unroll
            for (int tc = 0; tc < 4; ++tc) bfr[tc] = *(const short8*)(Bb + boff[tc]);
#pragma unroll
            for (int tr = 0; tr < 4; ++tr)
#pragma unroll
                for (int tc = 0; tc < 4; ++tc)
                    acc[tr][tc] = __builtin_amdgcn_mfma_f32_16x16x32_bf16(
                        af[tr], bfr[tc], acc[tr][tc], 0, 0, 0);
        }
        if (ks + 1 < 21) {
            asm volatile("s_waitcnt vmcnt(0)" ::: "memory");
            __syncthreads();
            cur ^= 1;
        }
    }
#undef STAGE

    // D mapping (R8-verified): per 16x16 tile, row = dq*4 + v, col = lp
#pragma unroll
    for (int tr = 0; tr < 4; ++tr) {
#pragma unroll
        for (int v = 0; v < 4; ++v) {
            const int p = p0 + wqp + tr * 16 + dq * 4 + v;
            if (p < NPAD) {
                float* srow_ = S + (size_t)p * NPAD;
#pragma unroll
                for (int tc = 0; tc < 4; ++tc) {
                    const int c = r0 + wqr + tc * 16 + lp;
                    if (c < NPAD) srow_[c] = acc[tr][tc][v];
                }
            }
        }
    }
}

// -------- stage 2b: block per (my, ly); box-sum + partial top-2 argmax --------
__global__ __launch_bounds__(384) void k_argmax(const float* __restrict__ S,
                                                const float* __restrict__ invNk,
                                                float* __restrict__ pval,
                                                float* __restrict__ psec,
                                                int* __restrict__ pidx, int batch) {
    __shared__ float band[3][50][50];
    const int t = threadIdx.x;
    const int my = blockIdx.x;     // 0..47
    const int ly = blockIdx.y;     // 0..47
    const int lx = t >> 3;         // 0..47
    const int mc = t & 7;          // 0..7

    for (int e = t; e < 7500; e += 384) {
        int i = e / 2500;
        int rem = e - i * 2500;
        int uu = rem / 50;
        int vv = rem - uu * 50;
        band[i][uu][vv] = S[(size_t)((ly + i) * 50 + uu) * NPAD + (my + i) * 50 + vv];
    }
    __syncthreads();

    const float* inb = invNk + batch * NPIX;
    float b1 = -FLT_MAX, b2 = -FLT_MAX;
    int i1 = 0x7FFFFFFF;

#pragma unroll
    for (int k = 0; k < 6; ++k) {
        int mx = mc + (k << 3);
        float s = 0.f;
#pragma unroll
        for (int i = 0; i < 3; ++i)
#pragma unroll
            for (int j = 0; j < 3; ++j)
                s += band[i][lx + j][mx + j];
        int m = my * 48 + mx;
        float v = s * inb[m];
        if (v > b1 || (v == b1 && m < i1)) { b2 = b1; b1 = v; i1 = m; }
        else b2 = fmaxf(b2, v);
    }
#pragma unroll
    for (int off = 1; off < 8; off <<= 1) {
        float ob1 = __shfl_xor(b1, off, 64);
        int oi1 = __shfl_xor(i1, off, 64);
        float ob2 = __shfl_xor(b2, off, 64);
        if (ob1 > b1 || (ob1 == b1 && oi1 < i1)) { b2 = fmaxf(b1, ob2); b1 = ob1; i1 = oi1; }
        else b2 = fmaxf(b2, ob1);
    }
    if (mc == 0) {
        int o = (batch * 48 + my) * NPIX + ly * 48 + lx;
        pval[o] = b1;
        psec[o] = b2;
        pidx[o] = i1;
    }
}

// per-batch merge over my partials
__global__ void k_argred(const float* __restrict__ pval, const float* __restrict__ psec,
                         const int* __restrict__ pidx, int* __restrict__ idxout,
                         int* __restrict__ flag, int b) {
    int lcl = blockIdx.x * 256 + threadIdx.x;
    if (lcl >= NPIX) return;
    float b1 = -FLT_MAX, b2 = -FLT_MAX;
    int i1 = 0x7FFFFFFF;
    for (int my = 0; my < 48; ++my) {
        int o = (b * 48 + my) * NPIX + lcl;
        float v1 = pval[o], v2 = psec[o];
        int ii = pidx[o];
        if (v1 > b1 || (v1 == b1 && ii < i1)) { b2 = fmaxf(b1, v2); b1 = v1; i1 = ii; }
        else b2 = fmaxf(b2, v1);
    }
    idxout[b * NPIX + lcl] = i1;
    flag[b * NPIX + lcl] = (b1 - b2 < MARGIN) ? 1 : 0;
}

// -------- candidate-pruned exact recheck: one wave per flagged row --------
__global__ __launch_bounds__(256) void k_fix2(const float* __restrict__ qp,
                                              const float* __restrict__ kp,
                                              const float* __restrict__ S,
                                              const float* __restrict__ invNk,
                                              const float* __restrict__ pval,
                                              const float* __restrict__ psec,
                                              const int* __restrict__ pidx,
                                              const int* __restrict__ flag,
                                              int* __restrict__ idx, int b) {
    const int t = threadIdx.x;
    const int lane = t & 63;
    const int row = blockIdx.x * 4 + (t >> 6);
    if (!flag[b * NPIX + row]) return;
    const float* Ap = qp + (size_t)b * PLANE;
    const float* Bp = kp + (size_t)b * PLANE;
    const float* inb = invNk + b * NPIX;
    const int ly = row / 48, lx = row % 48;

    float v1 = -FLT_MAX, v2 = -FLT_MAX;
    if (lane < 48) {
        int o = (b * 48 + lane) * NPIX + row;
        v1 = pval[o];
        v2 = psec[o];
    }
    float bb = v1;
#pragma unroll
    for (int off = 1; off < 64; off <<= 1)
        bb = fmaxf(bb, __shfl_xor(bb, off, 64));
    const float th = bb - MARGIN;

    unsigned long long mask = __ballot(lane < 48 && (v1 >= th || v2 >= th));
    float eb = -FLT_MAX;
    int ebi = 0x7FFFFFFF;
    while (mask) {
        const int my = __ffsll((long long)mask) - 1;
        mask &= mask - 1;
        float va = -FLT_MAX;
        if (lane < 48) {
            float s = 0.f;
#pragma unroll
            for (int i = 0; i < 3; ++i)
#pragma unroll
                for (int j = 0; j < 3; ++j)
                    s += S[(size_t)((ly + i) * 50 + lx + j) * NPAD + (my + i) * 50 + lane + j];
            va = s * inb[my * 48 + lane];
        }
        unsigned long long m2 = __ballot(lane < 48 && va >= th);
        while (m2) {
            const int mx = __ffsll((long long)m2) - 1;
            m2 &= m2 - 1;
            const int m = my * 48 + mx;
            float part = 0.f;
#pragma unroll
            for (int ij = 0; ij < 9; ++ij) {
                const float* qr = Ap + (size_t)((ly + ij / 3) * 50 + lx + ij % 3) * 224;
                const float* kr = Bp + (size_t)((my + ij / 3) * 50 + mx + ij % 3) * 224;
                for (int d = lane; d < 200; d += 64)
                    part = fmaf(qr[d], kr[d], part);
            }
#pragma unroll
            for (int off = 1; off < 64; off <<= 1)
                part += __shfl_xor(part, off, 64);
            const float v = part * inb[m];
            if (v > eb) { eb = v; ebi = m; }
        }
    }
    if (lane == 0 && ebi != 0x7FFFFFFF) idx[b * NPIX + row] = ebi;
}

// ---------------- stage 3a: per-(b,pixel) 9 source offsets ----------------
__global__ void k_soff(const int* __restrict__ idx, int* __restrict__ soff) {
    int t = blockIdx.x * 256 + threadIdx.x;
    if (t >= 2 * NPIX) return;
    int b = t / NPIX, pix = t - b * NPIX;
    int y = pix / 48, x = pix % 48;
#pragma unroll
    for (int i = 0; i < 3; ++i) {
#pragma unroll
        for (int j = 0; j < 3; ++j) {
            int u = i * 3 + j;
            int yq = y + 1 - i, xq = x + 1 - j;
            int so = -1;
            if (yq >= 0 && yq < 48 && xq >= 0 && xq < 48) {
                int m = idx[b * NPIX + yq * 48 + xq];
                int my = m / 48, mx = m % 48;
                int yy = my + i - 1, xx = mx + j - 1;
                if (yy >= 0 && yy < 48 && xx >= 0 && xx < 48) so = yy * 48 + xx;
            }
            soff[(b * 9 + u) * NPIX + pix] = so;
        }
    }
}

// ---------------- stage 3b: gather + fold via LDS-staged plane ----------------
#define CPB 4
__global__ __launch_bounds__(256) void k_out2(const float* __restrict__ x3,
                                              const int* __restrict__ soff,
                                              float* __restrict__ out) {
    __shared__ __align__(16) float plane[NPIX];
    const int t = threadIdx.x;
    const int img = blockIdx.x;
    const int b = img / 25, a = img % 25;

    int po[9][9];
#pragma unroll
    for (int u = 0; u < 9; ++u) {
        const int* sb = soff + (b * 9 + u) * NPIX;
#pragma unroll
        for (int k = 0; k < 9; ++k)
            po[k][u] = sb[k * 256 + t];
    }

    const size_t pbase = (size_t)b * 64 * 57600 + (size_t)a * 2304 +
                         (size_t)(blockIdx.y * CPB) * 57600;
    const float* gsrc = x3 + pbase;
    float* gdst = out + pbase;

    float4 r0, r1, r2;
    {
        const float4* g = (const float4*)gsrc;
        r0 = g[t]; r1 = g[t + 256];
        if (t < 64) r2 = g[t + 512];
    }
    float4* pl4 = (float4*)plane;
    pl4[t] = r0; pl4[t + 256] = r1;
    if (t < 64) pl4[t + 512] = r2;
    __syncthreads();

    for (int c = 0; c < CPB; ++c) {
        if (c + 1 < CPB) {
            const float4* g = (const float4*)(gsrc + (size_t)(c + 1) * 57600);
            r0 = g[t]; r1 = g[t + 256];
            if (t < 64) r2 = g[t + 512];
        }
        float* dst = gdst + (size_t)c * 57600;
#pragma unroll
        for (int k = 0; k < 9; ++k) {
            float acc = 0.f;
#pragma unroll
            for (int u = 0; u < 9; ++u) {
                int off = po[k][u];
                int ao = off < 0 ? 0 : off;
                float v = plane[ao];
                acc += (off < 0) ? 0.f : v;
            }
            dst[k * 256 + t] = acc;
        }
        __syncthreads();
        if (c + 1 < CPB) {
            pl4[t] = r0; pl4[t + 256] = r1;
            if (t < 64) pl4[t + 512] = r2;
        }
        __syncthreads();
    }
}

extern "C" void kernel_launch(void* const* d_in, const int* in_sizes, int n_in,
                              void* d_out, int out_size, void* d_ws, size_t ws_size,
                              hipStream_t stream) {
    const float* x1 = (const float*)d_in[0];
    const float* x2 = (const float*)d_in[1];
    const float* x3 = (const float*)d_in[2];
    const float* W  = (const float*)d_in[3];
    float* ws = (float*)d_ws;

    float* qp    = ws + OFF_QP;
    float* kp    = ws + OFF_KP;
    unsigned short* planes = (unsigned short*)(ws + OFF_PLANES);
    float* nk    = ws + OFF_NK;
    float* invNk = ws + OFF_INVNK;
    float* pval  = ws + OFF_PVAL;
    float* psec  = ws + OFF_PSEC;
    int*   pidx  = (int*)(ws + OFF_PIDX);
    int*   idx   = (int*)(ws + OFF_IDX);
    int*   flag  = (int*)(ws + OFF_FLAG);
    float* S     = ws + OFF_S;
    int*   soff  = (int*)(ws + OFF_SOFF);
    float* out   = (float*)d_out;

    // zero qp, kp and bf16 planes in one contiguous memset (padding rows/cols/d)
    hipMemsetAsync(qp, 0, (size_t)OFF_NK * sizeof(float), stream);

    k_qk<<<450, 256, 0, stream>>>(x1, x2, W, qp, kp, planes);
    k_nk<<<(2 * NPAD + 255) / 256, 256, 0, stream>>>(kp, nk);
    k_invnk<<<(2 * NPIX + 255) / 256, 256, 0, stream>>>(nk, invNk);

    for (int b = 0; b < 2; ++b) {
        k_mfma2<<<dim3(20, 20), 256, 0, stream>>>(planes, S, b);
        k_argmax<<<dim3(48, 48), 384, 0, stream>>>(S, invNk, pval, psec, pidx, b);
        k_argred<<<9, 256, 0, stream>>>(pval, psec, pidx, idx, flag, b);
        k_fix2<<<576, 256, 0, stream>>>(qp, kp, S, invNk, pval, psec, pidx, flag, idx, b);
    }
    k_soff<<<(2 * NPIX + 255) / 256, 256, 0, stream>>>(idx, soff);
    k_out2<<<dim3(50, 16), 256, 0, stream>>>(x3, soff, out);
}

// Round 10
// 255.177 us; speedup vs baseline: 1.0020x; 1.0020x over previous
//
#include <hip/hip_runtime.h>
#include <math.h>
#include <float.h>

#define NPIX 2304   // 48*48
#define NPAD 2500   // 50*50
#define PLANE 573440  // 2560*224 padded [p][d] fp32 plane per batch
#define MARGIN 3e-4f

// ws layout in floats
#define OFF_QP     0u         // [2][2560][224] fp32
#define OFF_KP     1146880u   // [2][2560][224] fp32
#define OFF_PLANES 2293760u   // 4 bf16 planes x 2 batches, blocked+swizzled (see k_qk)
#define OFF_NK     4587520u   // [2][2500]
#define OFF_INVNK  4592520u   // [2][2304]
#define OFF_PVAL   4597128u   // [2][48][2304]
#define OFF_PSEC   4818312u   // [2][48][2304]
#define OFF_PIDX   5039496u   // int [2][48][2304]
#define OFF_IDX    5260680u   // int [2][2304]
#define OFF_FLAG   5265288u   // int [2][2304]
#define OFF_S      5269896u   // [2500][2500] single batch (two-pass)
#define OFF_SOFF   OFF_S      // int [2][9][2304] — aliases S (S dead by then)
#define PLANE_SH   573440     // shorts per (plane, batch)

typedef __attribute__((ext_vector_type(8))) short short8;
typedef __attribute__((ext_vector_type(4))) float f32x4;

__device__ __forceinline__ unsigned short bfhi(float f) {
    unsigned u = __float_as_uint(f);
    return (unsigned short)((u + 0x7FFFu + ((u >> 16) & 1u)) >> 16);
}

__device__ __forceinline__ void gload_lds16(const void* g, void* l) {
    __builtin_amdgcn_global_load_lds(
        (const __attribute__((address_space(1))) unsigned int*)g,
        (__attribute__((address_space(3))) unsigned int*)l, 16, 0, 0);
}

// ---- fast zero: rocclr fillBuffer is latency-bound (~40us flat, 8% occupancy);
// a grid-stride float4 kernel does 18.3 MB in ~4-5 us.
__global__ __launch_bounds__(256) void k_zero(float4* __restrict__ p, int n4) {
    int i = blockIdx.x * 256 + threadIdx.x;
    const int stride = gridDim.x * 256;
    const float4 z = { 0.f, 0.f, 0.f, 0.f };
    for (; i < n4; i += stride) p[i] = z;
}

// ---- stage 1: q = W*x1, k = W*x2 -> fp32 [p][d] rows + bf16 hi/lo blocked planes ----
// bf16 plane layout (per plane, per batch): [panel P 0..19][chunk c 0..6][512 granules]
// granule = 8 bf16 = 16B; logical (row r 0..127, d-quad q 0..3) stored at granule
// G = r*4 + ((q + (r>>1)) & 3)  -> frag reads hit the 8-cycle LDS floor, and
// global_load_lds (linear lane*16B dest) reproduces this layout in LDS verbatim.
__global__ __launch_bounds__(256) void k_qk(const float* __restrict__ x1,
                                            const float* __restrict__ x2,
                                            const float* __restrict__ W,
                                            float* __restrict__ qp,
                                            float* __restrict__ kp,
                                            unsigned short* __restrict__ planes) {
    __shared__ float Ws[512];
    const int t = threadIdx.x;
    Ws[t] = W[t];
    Ws[t + 256] = W[t + 256];
    __syncthreads();
    const int img = blockIdx.x / 9;      // 0..49  (b*25 + a)
    const int chunk = blockIdx.x % 9;
    const int pix = chunk * 256 + t;     // 0..2303
    const int b = img / 25, a = img % 25;
    const int y = pix / 48, x = pix % 48;

    float q[8], k[8];
#pragma unroll
    for (int o = 0; o < 8; ++o) { q[o] = 0.f; k[o] = 0.f; }

    const float* p1 = x1 + (size_t)b * 64 * 57600 + a * 2304 + pix;
    const float* p2 = x2 + (size_t)b * 64 * 57600 + a * 2304 + pix;
    for (int c = 0; c < 64; ++c) {
        float v1 = p1[c * 57600];
        float v2 = p2[c * 57600];
#pragma unroll
        for (int o = 0; o < 8; ++o) {
            float w = Ws[o * 64 + c];
            q[o] = fmaf(w, v1, q[o]);
            k[o] = fmaf(w, v2, k[o]);
        }
    }
    const int p = (y + 1) * 50 + (x + 1);
    float* qd = qp + (size_t)b * PLANE + (size_t)p * 224 + a * 8;
    float* kd = kp + (size_t)b * PLANE + (size_t)p * 224 + a * 8;
    float4 q0 = { q[0], q[1], q[2], q[3] }, q1 = { q[4], q[5], q[6], q[7] };
    float4 k0 = { k[0], k[1], k[2], k[3] }, k1 = { k[4], k[5], k[6], k[7] };
    *(float4*)qd = q0; *(float4*)(qd + 4) = q1;
    *(float4*)kd = k0; *(float4*)(kd + 4) = k1;

    // bf16 hi/lo granules
    const int P = p >> 7, r = p & 127, cc = a >> 2, dq = a & 3;
    const int g = r * 4 + ((dq + (r >> 1)) & 3);
    const size_t goff = ((size_t)(P * 7 + cc) * 512 + g) * 8;
    short8 qh, ql, kh, kl;
#pragma unroll
    for (int o = 0; o < 8; ++o) {
        unsigned short h = bfhi(q[o]);
        qh[o] = (short)h;
        ql[o] = (short)bfhi(q[o] - __uint_as_float(((unsigned)h) << 16));
        h = bfhi(k[o]);
        kh[o] = (short)h;
        kl[o] = (short)bfhi(k[o] - __uint_as_float(((unsigned)h) << 16));
    }
    *(short8*)(planes + (size_t)(0 * 2 + b) * PLANE_SH + goff) = qh;
    *(short8*)(planes + (size_t)(1 * 2 + b) * PLANE_SH + goff) = ql;
    *(short8*)(planes + (size_t)(2 * 2 + b) * PLANE_SH + goff) = kh;
    *(short8*)(planes + (size_t)(3 * 2 + b) * PLANE_SH + goff) = kl;
}

// ---------------- per-position squared norms of k ----------------
__global__ void k_nk(const float* __restrict__ kp, float* __restrict__ nk) {
    int t = blockIdx.x * 256 + threadIdx.x;  // 0..4999
    if (t >= 2 * NPAD) return;
    int b = t / NPAD, p = t - b * NPAD;
    const float* src = kp + (size_t)b * PLANE + (size_t)p * 224;
    float s = 0.f;
    for (int d = 0; d < 200; d += 4) {
        float4 v = *(const float4*)(src + d);
        s = fmaf(v.x, v.x, s); s = fmaf(v.y, v.y, s);
        s = fmaf(v.z, v.z, s); s = fmaf(v.w, v.w, s);
    }
    nk[t] = s;
}

__global__ void k_invnk(const float* __restrict__ nk, float* __restrict__ invNk) {
    int t = blockIdx.x * 256 + threadIdx.x;  // 0..4607
    if (t >= 2 * NPIX) return;
    int b = t / NPIX, m = t - b * NPIX;
    int my = m / 48, mx = m % 48;
    const float* nb = nk + b * NPAD;
    float s = 0.f;
#pragma unroll
    for (int i = 0; i < 3; ++i)
#pragma unroll
        for (int j = 0; j < 3; ++j)
            s += nb[(my + i) * 50 + mx + j];
    invNk[t] = 1.0f / fmaxf(sqrtf(s), 1e-12f);
}

// ---- stage 2a: S ~= A^T B, 3-term bf16 split, global_load_lds staging, no in-loop cvt ----
__global__ __launch_bounds__(256, 2) void k_mfma2(const unsigned short* __restrict__ planes,
                                                  float* __restrict__ S, int b) {
    __shared__ unsigned short Abuf[2][4096];   // 128 rows x 32 d bf16, swizzled granules
    __shared__ unsigned short Bbuf[2][4096];
    const int t = threadIdx.x;
    // XCD-aware bijective swizzle (nwg = 400, %8 == 0)
    const int lin = blockIdx.y * gridDim.x + blockIdx.x;
    const int work = (lin & 7) * 50 + (lin >> 3);
    const int wy = work / 20, wx = work - (work / 20) * 20;

    const unsigned short* Ahi = planes + (size_t)(0 * 2 + b) * PLANE_SH;
    const unsigned short* Alo = planes + (size_t)(1 * 2 + b) * PLANE_SH;
    const unsigned short* Bhi = planes + (size_t)(2 * 2 + b) * PLANE_SH;
    const unsigned short* Blo = planes + (size_t)(3 * 2 + b) * PLANE_SH;

    const int p0 = wy * 128, r0 = wx * 128;
    const int wid = t >> 6, l = t & 63;
    const int lp = l & 15, dq = l >> 4;
    const int wqp = (wid >> 1) * 64, wqr = (wid & 1) * 64;

    // loop-invariant frag LDS offsets (shorts)
    int aoff[4], boff[4];
#pragma unroll
    for (int tr = 0; tr < 4; ++tr) {
        int rA = wqp + tr * 16 + lp;
        aoff[tr] = (rA * 4 + ((dq + (rA >> 1)) & 3)) * 8;
        int rB = wqr + tr * 16 + lp;
        boff[tr] = (rB * 4 + ((dq + (rB >> 1)) & 3)) * 8;
    }

    f32x4 acc[4][4];
#pragma unroll
    for (int i = 0; i < 4; ++i)
#pragma unroll
        for (int j = 0; j < 4; ++j) acc[i][j] = (f32x4){0.f, 0.f, 0.f, 0.f};

#define STAGE(buf, ks)                                                          \
    {                                                                           \
        const int term = (ks) / 7, c = (ks) - term * 7;                         \
        const unsigned short* gA = (term < 2 ? Ahi : Alo) + ((size_t)(wy * 7 + c) << 12); \
        const unsigned short* gB = (term != 1 ? Bhi : Blo) + ((size_t)(wx * 7 + c) << 12); \
        unsigned short* lA = &Abuf[buf][wid * 512];                             \
        unsigned short* lB = &Bbuf[buf][wid * 512];                             \
        gload_lds16(gA + t * 8, lA);                                            \
        gload_lds16(gA + 2048 + t * 8, lA + 2048);                              \
        gload_lds16(gB + t * 8, lB);                                            \
        gload_lds16(gB + 2048 + t * 8, lB + 2048);                              \
    }

    STAGE(0, 0);
    asm volatile("s_waitcnt vmcnt(0)" ::: "memory");
    __syncthreads();

    int cur = 0;
    for (int ks = 0; ks < 21; ++ks) {
        if (ks + 1 < 21) STAGE(cur ^ 1, ks + 1);
        {
            const unsigned short* Ab = &Abuf[cur][0];
            const unsigned short* Bb = &Bbuf[cur][0];
            short8 af[4], bfr[4];
#pragma unroll
            for (int tr = 0; tr < 4; ++tr) af[tr] = *(const short8*)(Ab + aoff[tr]);
#pragma unroll
            for (int tc = 0; tc < 4; ++tc) bfr[tc] = *(const short8*)(Bb + boff[tc]);
#pragma unroll
            for (int tr = 0; tr < 4; ++tr)
#pragma unroll
                for (int tc = 0; tc < 4; ++tc)
                    acc[tr][tc] = __builtin_amdgcn_mfma_f32_16x16x32_bf16(
                        af[tr], bfr[tc], acc[tr][tc], 0, 0, 0);
        }
        if (ks + 1 < 21) {
            asm volatile("s_waitcnt vmcnt(0)" ::: "memory");
            __syncthreads();
            cur ^= 1;
        }
    }
#undef STAGE

    // D mapping (R8-verified): per 16x16 tile, row = dq*4 + v, col = lp
#pragma unroll
    for (int tr = 0; tr < 4; ++tr) {
#pragma unroll
        for (int v = 0; v < 4; ++v) {
            const int p = p0 + wqp + tr * 16 + dq * 4 + v;
            if (p < NPAD) {
                float* srow_ = S + (size_t)p * NPAD;
#pragma unroll
                for (int tc = 0; tc < 4; ++tc) {
                    const int c = r0 + wqr + tc * 16 + lp;
                    if (c < NPAD) srow_[c] = acc[tr][tc][v];
                }
            }
        }
    }
}

// -------- stage 2b: block per (my, ly); box-sum + partial top-2 argmax --------
__global__ __launch_bounds__(384) void k_argmax(const float* __restrict__ S,
                                                const float* __restrict__ invNk,
                                                float* __restrict__ pval,
                                                float* __restrict__ psec,
                                                int* __restrict__ pidx, int batch) {
    __shared__ float band[3][50][50];
    const int t = threadIdx.x;
    const int my = blockIdx.x;     // 0..47
    const int ly = blockIdx.y;     // 0..47
    const int lx = t >> 3;         // 0..47
    const int mc = t & 7;          // 0..7

    for (int e = t; e < 7500; e += 384) {
        int i = e / 2500;
        int rem = e - i * 2500;
        int uu = rem / 50;
        int vv = rem - uu * 50;
        band[i][uu][vv] = S[(size_t)((ly + i) * 50 + uu) * NPAD + (my + i) * 50 + vv];
    }
    __syncthreads();

    const float* inb = invNk + batch * NPIX;
    float b1 = -FLT_MAX, b2 = -FLT_MAX;
    int i1 = 0x7FFFFFFF;

#pragma unroll
    for (int k = 0; k < 6; ++k) {
        int mx = mc + (k << 3);
        float s = 0.f;
#pragma unroll
        for (int i = 0; i < 3; ++i)
#pragma unroll
            for (int j = 0; j < 3; ++j)
                s += band[i][lx + j][mx + j];
        int m = my * 48 + mx;
        float v = s * inb[m];
        if (v > b1 || (v == b1 && m < i1)) { b2 = b1; b1 = v; i1 = m; }
        else b2 = fmaxf(b2, v);
    }
#pragma unroll
    for (int off = 1; off < 8; off <<= 1) {
        float ob1 = __shfl_xor(b1, off, 64);
        int oi1 = __shfl_xor(i1, off, 64);
        float ob2 = __shfl_xor(b2, off, 64);
        if (ob1 > b1 || (ob1 == b1 && oi1 < i1)) { b2 = fmaxf(b1, ob2); b1 = ob1; i1 = oi1; }
        else b2 = fmaxf(b2, ob1);
    }
    if (mc == 0) {
        int o = (batch * 48 + my) * NPIX + ly * 48 + lx;
        pval[o] = b1;
        psec[o] = b2;
        pidx[o] = i1;
    }
}

// per-batch merge over my partials
__global__ void k_argred(const float* __restrict__ pval, const float* __restrict__ psec,
                         const int* __restrict__ pidx, int* __restrict__ idxout,
                         int* __restrict__ flag, int b) {
    int lcl = blockIdx.x * 256 + threadIdx.x;
    if (lcl >= NPIX) return;
    float b1 = -FLT_MAX, b2 = -FLT_MAX;
    int i1 = 0x7FFFFFFF;
    for (int my = 0; my < 48; ++my) {
        int o = (b * 48 + my) * NPIX + lcl;
        float v1 = pval[o], v2 = psec[o];
        int ii = pidx[o];
        if (v1 > b1 || (v1 == b1 && ii < i1)) { b2 = fmaxf(b1, v2); b1 = v1; i1 = ii; }
        else b2 = fmaxf(b2, v1);
    }
    idxout[b * NPIX + lcl] = i1;
    flag[b * NPIX + lcl] = (b1 - b2 < MARGIN) ? 1 : 0;
}

// -------- candidate-pruned exact recheck: one wave per flagged row --------
__global__ __launch_bounds__(256) void k_fix2(const float* __restrict__ qp,
                                              const float* __restrict__ kp,
                                              const float* __restrict__ S,
                                              const float* __restrict__ invNk,
                                              const float* __restrict__ pval,
                                              const float* __restrict__ psec,
                                              const int* __restrict__ pidx,
                                              const int* __restrict__ flag,
                                              int* __restrict__ idx, int b) {
    const int t = threadIdx.x;
    const int lane = t & 63;
    const int row = blockIdx.x * 4 + (t >> 6);
    if (!flag[b * NPIX + row]) return;
    const float* Ap = qp + (size_t)b * PLANE;
    const float* Bp = kp + (size_t)b * PLANE;
    const float* inb = invNk + b * NPIX;
    const int ly = row / 48, lx = row % 48;

    float v1 = -FLT_MAX, v2 = -FLT_MAX;
    if (lane < 48) {
        int o = (b * 48 + lane) * NPIX + row;
        v1 = pval[o];
        v2 = psec[o];
    }
    float bb = v1;
#pragma unroll
    for (int off = 1; off < 64; off <<= 1)
        bb = fmaxf(bb, __shfl_xor(bb, off, 64));
    const float th = bb - MARGIN;

    unsigned long long mask = __ballot(lane < 48 && (v1 >= th || v2 >= th));
    float eb = -FLT_MAX;
    int ebi = 0x7FFFFFFF;
    while (mask) {
        const int my = __ffsll((long long)mask) - 1;
        mask &= mask - 1;
        float va = -FLT_MAX;
        if (lane < 48) {
            float s = 0.f;
#pragma unroll
            for (int i = 0; i < 3; ++i)
#pragma unroll
                for (int j = 0; j < 3; ++j)
                    s += S[(size_t)((ly + i) * 50 + lx + j) * NPAD + (my + i) * 50 + lane + j];
            va = s * inb[my * 48 + lane];
        }
        unsigned long long m2 = __ballot(lane < 48 && va >= th);
        while (m2) {
            const int mx = __ffsll((long long)m2) - 1;
            m2 &= m2 - 1;
            const int m = my * 48 + mx;
            float part = 0.f;
#pragma unroll
            for (int ij = 0; ij < 9; ++ij) {
                const float* qr = Ap + (size_t)((ly + ij / 3) * 50 + lx + ij % 3) * 224;
                const float* kr = Bp + (size_t)((my + ij / 3) * 50 + mx + ij % 3) * 224;
                for (int d = lane; d < 200; d += 64)
                    part = fmaf(qr[d], kr[d], part);
            }
#pragma unroll
            for (int off = 1; off < 64; off <<= 1)
                part += __shfl_xor(part, off, 64);
            const float v = part * inb[m];
            if (v > eb) { eb = v; ebi = m; }
        }
    }
    if (lane == 0 && ebi != 0x7FFFFFFF) idx[b * NPIX + row] = ebi;
}

// ---------------- stage 3a: per-(b,pixel) 9 source offsets ----------------
__global__ void k_soff(const int* __restrict__ idx, int* __restrict__ soff) {
    int t = blockIdx.x * 256 + threadIdx.x;
    if (t >= 2 * NPIX) return;
    int b = t / NPIX, pix = t - b * NPIX;
    int y = pix / 48, x = pix % 48;
#pragma unroll
    for (int i = 0; i < 3; ++i) {
#pragma unroll
        for (int j = 0; j < 3; ++j) {
            int u = i * 3 + j;
            int yq = y + 1 - i, xq = x + 1 - j;
            int so = -1;
            if (yq >= 0 && yq < 48 && xq >= 0 && xq < 48) {
                int m = idx[b * NPIX + yq * 48 + xq];
                int my = m / 48, mx = m % 48;
                int yy = my + i - 1, xx = mx + j - 1;
                if (yy >= 0 && yy < 48 && xx >= 0 && xx < 48) so = yy * 48 + xx;
            }
            soff[(b * 9 + u) * NPIX + pix] = so;
        }
    }
}

// ---------------- stage 3b: gather + fold via LDS-staged plane ----------------
#define CPB 4
__global__ __launch_bounds__(256) void k_out2(const float* __restrict__ x3,
                                              const int* __restrict__ soff,
                                              float* __restrict__ out) {
    __shared__ __align__(16) float plane[NPIX];
    const int t = threadIdx.x;
    const int img = blockIdx.x;
    const int b = img / 25, a = img % 25;

    int po[9][9];
#pragma unroll
    for (int u = 0; u < 9; ++u) {
        const int* sb = soff + (b * 9 + u) * NPIX;
#pragma unroll
        for (int k = 0; k < 9; ++k)
            po[k][u] = sb[k * 256 + t];
    }

    const size_t pbase = (size_t)b * 64 * 57600 + (size_t)a * 2304 +
                         (size_t)(blockIdx.y * CPB) * 57600;
    const float* gsrc = x3 + pbase;
    float* gdst = out + pbase;

    float4 r0, r1, r2;
    {
        const float4* g = (const float4*)gsrc;
        r0 = g[t]; r1 = g[t + 256];
        if (t < 64) r2 = g[t + 512];
    }
    float4* pl4 = (float4*)plane;
    pl4[t] = r0; pl4[t + 256] = r1;
    if (t < 64) pl4[t + 512] = r2;
    __syncthreads();

    for (int c = 0; c < CPB; ++c) {
        if (c + 1 < CPB) {
            const float4* g = (const float4*)(gsrc + (size_t)(c + 1) * 57600);
            r0 = g[t]; r1 = g[t + 256];
            if (t < 64) r2 = g[t + 512];
        }
        float* dst = gdst + (size_t)c * 57600;
#pragma unroll
        for (int k = 0; k < 9; ++k) {
            float acc = 0.f;
#pragma unroll
            for (int u = 0; u < 9; ++u) {
                int off = po[k][u];
                int ao = off < 0 ? 0 : off;
                float v = plane[ao];
                acc += (off < 0) ? 0.f : v;
            }
            dst[k * 256 + t] = acc;
        }
        __syncthreads();
        if (c + 1 < CPB) {
            pl4[t] = r0; pl4[t + 256] = r1;
            if (t < 64) pl4[t + 512] = r2;
        }
        __syncthreads();
    }
}

extern "C" void kernel_launch(void* const* d_in, const int* in_sizes, int n_in,
                              void* d_out, int out_size, void* d_ws, size_t ws_size,
                              hipStream_t stream) {
    const float* x1 = (const float*)d_in[0];
    const float* x2 = (const float*)d_in[1];
    const float* x3 = (const float*)d_in[2];
    const float* W  = (const float*)d_in[3];
    float* ws = (float*)d_ws;

    float* qp    = ws + OFF_QP;
    float* kp    = ws + OFF_KP;
    unsigned short* planes = (unsigned short*)(ws + OFF_PLANES);
    float* nk    = ws + OFF_NK;
    float* invNk = ws + OFF_INVNK;
    float* pval  = ws + OFF_PVAL;
    float* psec  = ws + OFF_PSEC;
    int*   pidx  = (int*)(ws + OFF_PIDX);
    int*   idx   = (int*)(ws + OFF_IDX);
    int*   flag  = (int*)(ws + OFF_FLAG);
    float* S     = ws + OFF_S;
    int*   soff  = (int*)(ws + OFF_SOFF);
    float* out   = (float*)d_out;

    // zero qp, kp and bf16 planes (padding rows/cols/d-tail) — custom kernel,
    // NOT hipMemsetAsync: rocclr fill is latency-bound (~40us flat for MB-scale).
    k_zero<<<2048, 256, 0, stream>>>((float4*)(ws + OFF_QP), (int)(OFF_NK / 4));

    k_qk<<<450, 256, 0, stream>>>(x1, x2, W, qp, kp, planes);
    k_nk<<<(2 * NPAD + 255) / 256, 256, 0, stream>>>(kp, nk);
    k_invnk<<<(2 * NPIX + 255) / 256, 256, 0, stream>>>(nk, invNk);

    for (int b = 0; b < 2; ++b) {
        k_mfma2<<<dim3(20, 20), 256, 0, stream>>>(planes, S, b);
        k_argmax<<<dim3(48, 48), 384, 0, stream>>>(S, invNk, pval, psec, pidx, b);
        k_argred<<<9, 256, 0, stream>>>(pval, psec, pidx, idx, flag, b);
        k_fix2<<<576, 256, 0, stream>>>(qp, kp, S, invNk, pval, psec, pidx, flag, idx, b);
    }
    k_soff<<<(2 * NPIX + 255) / 256, 256, 0, stream>>>(idx, soff);
    k_out2<<<dim3(50, 16), 256, 0, stream>>>(x3, soff, out);
}

// Round 11
// 185.364 us; speedup vs baseline: 1.3794x; 1.3766x over previous
//
#include <hip/hip_runtime.h>
#include <math.h>
#include <float.h>

#define NPIX 2304   // 48*48
#define NPAD 2500   // 50*50
#define PLANE 573440  // 2560*224 padded [p][d] fp32 plane per batch
#define MARGIN 3e-4f

// ws layout in floats
#define OFF_QP     0u         // [2][2560][224] fp32
#define OFF_KP     1146880u   // [2][2560][224] fp32
#define OFF_PLANES 2293760u   // 4 bf16 planes x 2 batches, blocked+swizzled (see k_qk)
#define OFF_NK     4587520u   // [2][2500]
#define OFF_INVNK  4592520u   // [2][2304]
#define OFF_PVAL   4597128u   // [2][48][2304]
#define OFF_PSEC   4818312u   // [2][48][2304]
#define OFF_PIDX   5039496u   // int [2][48][2304]
#define OFF_IDX    5260680u   // int [2][2304]
#define OFF_FLAG   5265288u   // int [2][2304]
#define OFF_S      5269896u   // [z][2500][2500] (2 buffers if ws permits, else 1)
#define OFF_SOFF   OFF_S      // int [2][9][2304] — aliases S (S dead by then)
#define SSTRIDE    6250000L
#define PLANE_SH   573440     // shorts per (plane, batch)

typedef __attribute__((ext_vector_type(8))) short short8;
typedef __attribute__((ext_vector_type(4))) float f32x4;

__device__ __forceinline__ unsigned short bfhi(float f) {
    unsigned u = __float_as_uint(f);
    return (unsigned short)((u + 0x7FFFu + ((u >> 16) & 1u)) >> 16);
}

__device__ __forceinline__ void gload_lds16(const void* g, void* l) {
    __builtin_amdgcn_global_load_lds(
        (const __attribute__((address_space(1))) unsigned int*)g,
        (__attribute__((address_space(3))) unsigned int*)l, 16, 0, 0);
}

// ---- fast zero (rocclr fill is latency-bound; this hits BW) ----
__global__ __launch_bounds__(256) void k_zero(float4* __restrict__ p, int n4) {
    int i = blockIdx.x * 256 + threadIdx.x;
    const int stride = gridDim.x * 256;
    const float4 z = { 0.f, 0.f, 0.f, 0.f };
    for (; i < n4; i += stride) p[i] = z;
}

// ---- stage 1: q = W*x1, k = W*x2 -> fp32 [p][d] rows + bf16 hi/lo blocked planes ----
// bf16 plane layout (per plane, per batch): [panel P 0..19][chunk c 0..6][512 granules]
// granule = 8 bf16 = 16B; logical (row r, d-quad q) at granule G = r*4 + ((q+(r>>1))&3)
// -> frag reads hit the 8-cycle LDS floor; global_load_lds (linear lane*16B dest)
// reproduces this layout in LDS verbatim.
__global__ __launch_bounds__(256) void k_qk(const float* __restrict__ x1,
                                            const float* __restrict__ x2,
                                            const float* __restrict__ W,
                                            float* __restrict__ qp,
                                            float* __restrict__ kp,
                                            unsigned short* __restrict__ planes) {
    __shared__ float Ws[512];
    const int t = threadIdx.x;
    Ws[t] = W[t];
    Ws[t + 256] = W[t + 256];
    __syncthreads();
    const int img = blockIdx.x / 9;      // 0..49  (b*25 + a)
    const int chunk = blockIdx.x % 9;
    const int pix = chunk * 256 + t;     // 0..2303
    const int b = img / 25, a = img % 25;
    const int y = pix / 48, x = pix % 48;

    float q[8], k[8];
#pragma unroll
    for (int o = 0; o < 8; ++o) { q[o] = 0.f; k[o] = 0.f; }

    const float* p1 = x1 + (size_t)b * 64 * 57600 + a * 2304 + pix;
    const float* p2 = x2 + (size_t)b * 64 * 57600 + a * 2304 + pix;
    for (int c = 0; c < 64; ++c) {
        float v1 = p1[c * 57600];
        float v2 = p2[c * 57600];
#pragma unroll
        for (int o = 0; o < 8; ++o) {
            float w = Ws[o * 64 + c];
            q[o] = fmaf(w, v1, q[o]);
            k[o] = fmaf(w, v2, k[o]);
        }
    }
    const int p = (y + 1) * 50 + (x + 1);
    float* qd = qp + (size_t)b * PLANE + (size_t)p * 224 + a * 8;
    float* kd = kp + (size_t)b * PLANE + (size_t)p * 224 + a * 8;
    float4 q0 = { q[0], q[1], q[2], q[3] }, q1 = { q[4], q[5], q[6], q[7] };
    float4 k0 = { k[0], k[1], k[2], k[3] }, k1 = { k[4], k[5], k[6], k[7] };
    *(float4*)qd = q0; *(float4*)(qd + 4) = q1;
    *(float4*)kd = k0; *(float4*)(kd + 4) = k1;

    // bf16 hi/lo granules
    const int P = p >> 7, r = p & 127, cc = a >> 2, dq = a & 3;
    const int g = r * 4 + ((dq + (r >> 1)) & 3);
    const size_t goff = ((size_t)(P * 7 + cc) * 512 + g) * 8;
    short8 qh, ql, kh, kl;
#pragma unroll
    for (int o = 0; o < 8; ++o) {
        unsigned short h = bfhi(q[o]);
        qh[o] = (short)h;
        ql[o] = (short)bfhi(q[o] - __uint_as_float(((unsigned)h) << 16));
        h = bfhi(k[o]);
        kh[o] = (short)h;
        kl[o] = (short)bfhi(k[o] - __uint_as_float(((unsigned)h) << 16));
    }
    *(short8*)(planes + (size_t)(0 * 2 + b) * PLANE_SH + goff) = qh;
    *(short8*)(planes + (size_t)(1 * 2 + b) * PLANE_SH + goff) = ql;
    *(short8*)(planes + (size_t)(2 * 2 + b) * PLANE_SH + goff) = kh;
    *(short8*)(planes + (size_t)(3 * 2 + b) * PLANE_SH + goff) = kl;
}

// ---------------- per-position squared norms of k ----------------
__global__ void k_nk(const float* __restrict__ kp, float* __restrict__ nk) {
    int t = blockIdx.x * 256 + threadIdx.x;  // 0..4999
    if (t >= 2 * NPAD) return;
    int b = t / NPAD, p = t - b * NPAD;
    const float* src = kp + (size_t)b * PLANE + (size_t)p * 224;
    float s = 0.f;
    for (int d = 0; d < 200; d += 4) {
        float4 v = *(const float4*)(src + d);
        s = fmaf(v.x, v.x, s); s = fmaf(v.y, v.y, s);
        s = fmaf(v.z, v.z, s); s = fmaf(v.w, v.w, s);
    }
    nk[t] = s;
}

__global__ void k_invnk(const float* __restrict__ nk, float* __restrict__ invNk) {
    int t = blockIdx.x * 256 + threadIdx.x;  // 0..4607
    if (t >= 2 * NPIX) return;
    int b = t / NPIX, m = t - b * NPIX;
    int my = m / 48, mx = m % 48;
    const float* nb = nk + b * NPAD;
    float s = 0.f;
#pragma unroll
    for (int i = 0; i < 3; ++i)
#pragma unroll
        for (int j = 0; j < 3; ++j)
            s += nb[(my + i) * 50 + mx + j];
    invNk[t] = 1.0f / fmaxf(sqrtf(s), 1e-12f);
}

// ---- stage 2a: S ~= A^T B, 3-term bf16 split, global_load_lds staging ----
// nwork = 400 * NZ (z in work-id); XCD swizzle over the whole fused grid.
__global__ __launch_bounds__(256, 2) void k_mfma2(const unsigned short* __restrict__ planes,
                                                  float* __restrict__ S,
                                                  long sStride, int bofs) {
    __shared__ unsigned short Abuf[2][4096];   // 128 rows x 32 d bf16, swizzled granules
    __shared__ unsigned short Bbuf[2][4096];
    const int t = threadIdx.x;
    const int nwg = gridDim.x * gridDim.y * gridDim.z;   // 400 or 800, %8==0
    const int lin = (blockIdx.z * gridDim.y + blockIdx.y) * gridDim.x + blockIdx.x;
    const int work = (lin & 7) * (nwg >> 3) + (lin >> 3);
    const int z = work / 400;
    const int rem = work - z * 400;
    const int wy = rem / 20, wx = rem - (rem / 20) * 20;
    const int b = bofs + z;

    const unsigned short* Ahi = planes + (size_t)(0 * 2 + b) * PLANE_SH;
    const unsigned short* Alo = planes + (size_t)(1 * 2 + b) * PLANE_SH;
    const unsigned short* Bhi = planes + (size_t)(2 * 2 + b) * PLANE_SH;
    const unsigned short* Blo = planes + (size_t)(3 * 2 + b) * PLANE_SH;
    float* Sb = S + (size_t)z * sStride;

    const int p0 = wy * 128, r0 = wx * 128;
    const int wid = t >> 6, l = t & 63;
    const int lp = l & 15, dq = l >> 4;
    const int wqp = (wid >> 1) * 64, wqr = (wid & 1) * 64;

    // loop-invariant frag LDS offsets (shorts)
    int aoff[4], boff[4];
#pragma unroll
    for (int tr = 0; tr < 4; ++tr) {
        int rA = wqp + tr * 16 + lp;
        aoff[tr] = (rA * 4 + ((dq + (rA >> 1)) & 3)) * 8;
        int rB = wqr + tr * 16 + lp;
        boff[tr] = (rB * 4 + ((dq + (rB >> 1)) & 3)) * 8;
    }

    f32x4 acc[4][4];
#pragma unroll
    for (int i = 0; i < 4; ++i)
#pragma unroll
        for (int j = 0; j < 4; ++j) acc[i][j] = (f32x4){0.f, 0.f, 0.f, 0.f};

#define STAGE(buf, ks)                                                          \
    {                                                                           \
        const int term = (ks) / 7, c = (ks) - term * 7;                         \
        const unsigned short* gA = (term < 2 ? Ahi : Alo) + ((size_t)(wy * 7 + c) << 12); \
        const unsigned short* gB = (term != 1 ? Bhi : Blo) + ((size_t)(wx * 7 + c) << 12); \
        unsigned short* lA = &Abuf[buf][wid * 512];                             \
        unsigned short* lB = &Bbuf[buf][wid * 512];                             \
        gload_lds16(gA + t * 8, lA);                                            \
        gload_lds16(gA + 2048 + t * 8, lA + 2048);                              \
        gload_lds16(gB + t * 8, lB);                                            \
        gload_lds16(gB + 2048 + t * 8, lB + 2048);                              \
    }

    STAGE(0, 0);
    asm volatile("s_waitcnt vmcnt(0)" ::: "memory");
    __syncthreads();

    int cur = 0;
    for (int ks = 0; ks < 21; ++ks) {
        if (ks + 1 < 21) STAGE(cur ^ 1, ks + 1);
        {
            const unsigned short* Ab = &Abuf[cur][0];
            const unsigned short* Bb = &Bbuf[cur][0];
            short8 af[4], bfr[4];
#pragma unroll
            for (int tr = 0; tr < 4; ++tr) af[tr] = *(const short8*)(Ab + aoff[tr]);
#pragma unroll
            for (int tc = 0; tc < 4; ++tc) bfr[tc] = *(const short8*)(Bb + boff[tc]);
#pragma unroll
            for (int tr = 0; tr < 4; ++tr)
#pragma unroll
                for (int tc = 0; tc < 4; ++tc)
                    acc[tr][tc] = __builtin_amdgcn_mfma_f32_16x16x32_bf16(
                        af[tr], bfr[tc], acc[tr][tc], 0, 0, 0);
        }
        if (ks + 1 < 21) {
            asm volatile("s_waitcnt vmcnt(0)" ::: "memory");
            __syncthreads();
            cur ^= 1;
        }
    }
#undef STAGE

    // D mapping (R8-verified): per 16x16 tile, row = dq*4 + v, col = lp
#pragma unroll
    for (int tr = 0; tr < 4; ++tr) {
#pragma unroll
        for (int v = 0; v < 4; ++v) {
            const int p = p0 + wqp + tr * 16 + dq * 4 + v;
            if (p < NPAD) {
                float* srow_ = Sb + (size_t)p * NPAD;
#pragma unroll
                for (int tc = 0; tc < 4; ++tc) {
                    const int c = r0 + wqr + tc * 16 + lp;
                    if (c < NPAD) srow_[c] = acc[tr][tc][v];
                }
            }
        }
    }
}

// -------- stage 2b: block per (my, ly, z); box-sum + partial top-2 argmax --------
__global__ __launch_bounds__(384) void k_argmax(const float* __restrict__ S,
                                                const float* __restrict__ invNk,
                                                float* __restrict__ pval,
                                                float* __restrict__ psec,
                                                int* __restrict__ pidx,
                                                long sStride, int bofs) {
    __shared__ float band[3][50][50];
    const int t = threadIdx.x;
    const int my = blockIdx.x;     // 0..47
    const int ly = blockIdx.y;     // 0..47
    const int batch = bofs + blockIdx.z;
    const float* Sb = S + (size_t)blockIdx.z * sStride;
    const int lx = t >> 3;         // 0..47
    const int mc = t & 7;          // 0..7

    for (int e = t; e < 7500; e += 384) {
        int i = e / 2500;
        int rem = e - i * 2500;
        int uu = rem / 50;
        int vv = rem - uu * 50;
        band[i][uu][vv] = Sb[(size_t)((ly + i) * 50 + uu) * NPAD + (my + i) * 50 + vv];
    }
    __syncthreads();

    const float* inb = invNk + batch * NPIX;
    float b1 = -FLT_MAX, b2 = -FLT_MAX;
    int i1 = 0x7FFFFFFF;

#pragma unroll
    for (int k = 0; k < 6; ++k) {
        int mx = mc + (k << 3);
        float s = 0.f;
#pragma unroll
        for (int i = 0; i < 3; ++i)
#pragma unroll
            for (int j = 0; j < 3; ++j)
                s += band[i][lx + j][mx + j];
        int m = my * 48 + mx;
        float v = s * inb[m];
        if (v > b1 || (v == b1 && m < i1)) { b2 = b1; b1 = v; i1 = m; }
        else b2 = fmaxf(b2, v);
    }
#pragma unroll
    for (int off = 1; off < 8; off <<= 1) {
        float ob1 = __shfl_xor(b1, off, 64);
        int oi1 = __shfl_xor(i1, off, 64);
        float ob2 = __shfl_xor(b2, off, 64);
        if (ob1 > b1 || (ob1 == b1 && oi1 < i1)) { b2 = fmaxf(b1, ob2); b1 = ob1; i1 = oi1; }
        else b2 = fmaxf(b2, ob1);
    }
    if (mc == 0) {
        int o = (batch * 48 + my) * NPIX + ly * 48 + lx;
        pval[o] = b1;
        psec[o] = b2;
        pidx[o] = i1;
    }
}

// merge over my partials (both batches in one launch)
__global__ void k_argred(const float* __restrict__ pval, const float* __restrict__ psec,
                         const int* __restrict__ pidx, int* __restrict__ idxout,
                         int* __restrict__ flag) {
    int t = blockIdx.x * 256 + threadIdx.x;
    if (t >= 2 * NPIX) return;
    int b = t / NPIX, lcl = t - b * NPIX;
    float b1 = -FLT_MAX, b2 = -FLT_MAX;
    int i1 = 0x7FFFFFFF;
    for (int my = 0; my < 48; ++my) {
        int o = (b * 48 + my) * NPIX + lcl;
        float v1 = pval[o], v2 = psec[o];
        int ii = pidx[o];
        if (v1 > b1 || (v1 == b1 && ii < i1)) { b2 = fmaxf(b1, v2); b1 = v1; i1 = ii; }
        else b2 = fmaxf(b2, v1);
    }
    idxout[t] = i1;
    flag[t] = (b1 - b2 < MARGIN) ? 1 : 0;
}

// -------- candidate-pruned exact recheck: one wave per flagged row --------
__global__ __launch_bounds__(256) void k_fix2(const float* __restrict__ qp,
                                              const float* __restrict__ kp,
                                              const float* __restrict__ S,
                                              const float* __restrict__ invNk,
                                              const float* __restrict__ pval,
                                              const float* __restrict__ psec,
                                              const int* __restrict__ pidx,
                                              const int* __restrict__ flag,
                                              int* __restrict__ idx,
                                              long sStride, int bofs) {
    const int t = threadIdx.x;
    const int lane = t & 63;
    const int row = blockIdx.x * 4 + (t >> 6);
    const int z = blockIdx.y;
    const int b = bofs + z;
    if (!flag[b * NPIX + row]) return;
    const float* Sb = S + (size_t)z * sStride;
    const float* Ap = qp + (size_t)b * PLANE;
    const float* Bp = kp + (size_t)b * PLANE;
    const float* inb = invNk + b * NPIX;
    const int ly = row / 48, lx = row % 48;

    float v1 = -FLT_MAX, v2 = -FLT_MAX;
    if (lane < 48) {
        int o = (b * 48 + lane) * NPIX + row;
        v1 = pval[o];
        v2 = psec[o];
    }
    float bb = v1;
#pragma unroll
    for (int off = 1; off < 64; off <<= 1)
        bb = fmaxf(bb, __shfl_xor(bb, off, 64));
    const float th = bb - MARGIN;

    unsigned long long mask = __ballot(lane < 48 && (v1 >= th || v2 >= th));
    float eb = -FLT_MAX;
    int ebi = 0x7FFFFFFF;
    while (mask) {
        const int my = __ffsll((long long)mask) - 1;
        mask &= mask - 1;
        float va = -FLT_MAX;
        if (lane < 48) {
            float s = 0.f;
#pragma unroll
            for (int i = 0; i < 3; ++i)
#pragma unroll
                for (int j = 0; j < 3; ++j)
                    s += Sb[(size_t)((ly + i) * 50 + lx + j) * NPAD + (my + i) * 50 + lane + j];
            va = s * inb[my * 48 + lane];
        }
        unsigned long long m2 = __ballot(lane < 48 && va >= th);
        while (m2) {
            const int mx = __ffsll((long long)m2) - 1;
            m2 &= m2 - 1;
            const int m = my * 48 + mx;
            float part = 0.f;
#pragma unroll
            for (int ij = 0; ij < 9; ++ij) {
                const float* qr = Ap + (size_t)((ly + ij / 3) * 50 + lx + ij % 3) * 224;
                const float* kr = Bp + (size_t)((my + ij / 3) * 50 + mx + ij % 3) * 224;
                for (int d = lane; d < 200; d += 64)
                    part = fmaf(qr[d], kr[d], part);
            }
#pragma unroll
            for (int off = 1; off < 64; off <<= 1)
                part += __shfl_xor(part, off, 64);
            const float v = part * inb[m];
            if (v > eb) { eb = v; ebi = m; }
        }
    }
    if (lane == 0 && ebi != 0x7FFFFFFF) idx[b * NPIX + row] = ebi;
}

// ---------------- stage 3a: per-(b,pixel) 9 source offsets ----------------
__global__ void k_soff(const int* __restrict__ idx, int* __restrict__ soff) {
    int t = blockIdx.x * 256 + threadIdx.x;
    if (t >= 2 * NPIX) return;
    int b = t / NPIX, pix = t - b * NPIX;
    int y = pix / 48, x = pix % 48;
#pragma unroll
    for (int i = 0; i < 3; ++i) {
#pragma unroll
        for (int j = 0; j < 3; ++j) {
            int u = i * 3 + j;
            int yq = y + 1 - i, xq = x + 1 - j;
            int so = -1;
            if (yq >= 0 && yq < 48 && xq >= 0 && xq < 48) {
                int m = idx[b * NPIX + yq * 48 + xq];
                int my = m / 48, mx = m % 48;
                int yy = my + i - 1, xx = mx + j - 1;
                if (yy >= 0 && yy < 48 && xx >= 0 && xx < 48) so = yy * 48 + xx;
            }
            soff[(b * 9 + u) * NPIX + pix] = so;
        }
    }
}

// ---------------- stage 3b: gather + fold via LDS-staged plane ----------------
#define CPB 4
__global__ __launch_bounds__(256) void k_out2(const float* __restrict__ x3,
                                              const int* __restrict__ soff,
                                              float* __restrict__ out) {
    __shared__ __align__(16) float plane[NPIX];
    const int t = threadIdx.x;
    const int img = blockIdx.x;
    const int b = img / 25, a = img % 25;

    int po[9][9];
#pragma unroll
    for (int u = 0; u < 9; ++u) {
        const int* sb = soff + (b * 9 + u) * NPIX;
#pragma unroll
        for (int k = 0; k < 9; ++k)
            po[k][u] = sb[k * 256 + t];
    }

    const size_t pbase = (size_t)b * 64 * 57600 + (size_t)a * 2304 +
                         (size_t)(blockIdx.y * CPB) * 57600;
    const float* gsrc = x3 + pbase;
    float* gdst = out + pbase;

    float4 r0, r1, r2;
    {
        const float4* g = (const float4*)gsrc;
        r0 = g[t]; r1 = g[t + 256];
        if (t < 64) r2 = g[t + 512];
    }
    float4* pl4 = (float4*)plane;
    pl4[t] = r0; pl4[t + 256] = r1;
    if (t < 64) pl4[t + 512] = r2;
    __syncthreads();

    for (int c = 0; c < CPB; ++c) {
        if (c + 1 < CPB) {
            const float4* g = (const float4*)(gsrc + (size_t)(c + 1) * 57600);
            r0 = g[t]; r1 = g[t + 256];
            if (t < 64) r2 = g[t + 512];
        }
        float* dst = gdst + (size_t)c * 57600;
#pragma unroll
        for (int k = 0; k < 9; ++k) {
            float acc = 0.f;
#pragma unroll
            for (int u = 0; u < 9; ++u) {
                int off = po[k][u];
                int ao = off < 0 ? 0 : off;
                float v = plane[ao];
                acc += (off < 0) ? 0.f : v;
            }
            dst[k * 256 + t] = acc;
        }
        __syncthreads();
        if (c + 1 < CPB) {
            pl4[t] = r0; pl4[t + 256] = r1;
            if (t < 64) pl4[t + 512] = r2;
        }
        __syncthreads();
    }
}

extern "C" void kernel_launch(void* const* d_in, const int* in_sizes, int n_in,
                              void* d_out, int out_size, void* d_ws, size_t ws_size,
                              hipStream_t stream) {
    const float* x1 = (const float*)d_in[0];
    const float* x2 = (const float*)d_in[1];
    const float* x3 = (const float*)d_in[2];
    const float* W  = (const float*)d_in[3];
    float* ws = (float*)d_ws;

    float* qp    = ws + OFF_QP;
    float* kp    = ws + OFF_KP;
    unsigned short* planes = (unsigned short*)(ws + OFF_PLANES);
    float* nk    = ws + OFF_NK;
    float* invNk = ws + OFF_INVNK;
    float* pval  = ws + OFF_PVAL;
    float* psec  = ws + OFF_PSEC;
    int*   pidx  = (int*)(ws + OFF_PIDX);
    int*   idx   = (int*)(ws + OFF_IDX);
    int*   flag  = (int*)(ws + OFF_FLAG);
    float* S     = ws + OFF_S;
    int*   soff  = (int*)(ws + OFF_SOFF);
    float* out   = (float*)d_out;

    const bool bigS = ws_size >= (size_t)(OFF_S + 2UL * (unsigned long)SSTRIDE) * 4UL;

    // zero qp/kp/planes (padding) — custom kernel, not latency-bound rocclr fill
    k_zero<<<2048, 256, 0, stream>>>((float4*)(ws + OFF_QP), (int)(OFF_NK / 4));

    k_qk<<<450, 256, 0, stream>>>(x1, x2, W, qp, kp, planes);
    k_nk<<<(2 * NPAD + 255) / 256, 256, 0, stream>>>(kp, nk);
    k_invnk<<<(2 * NPIX + 255) / 256, 256, 0, stream>>>(nk, invNk);

    if (bigS) {
        k_mfma2<<<dim3(20, 20, 2), 256, 0, stream>>>(planes, S, SSTRIDE, 0);
        k_argmax<<<dim3(48, 48, 2), 384, 0, stream>>>(S, invNk, pval, psec, pidx, SSTRIDE, 0);
        k_argred<<<18, 256, 0, stream>>>(pval, psec, pidx, idx, flag);
        k_fix2<<<dim3(576, 2), 256, 0, stream>>>(qp, kp, S, invNk, pval, psec, pidx,
                                                 flag, idx, SSTRIDE, 0);
    } else {
        for (int b = 0; b < 2; ++b) {
            k_mfma2<<<dim3(20, 20, 1), 256, 0, stream>>>(planes, S, 0L, b);
            k_argmax<<<dim3(48, 48, 1), 384, 0, stream>>>(S, invNk, pval, psec, pidx, 0L, b);
            if (b == 1) k_argred<<<18, 256, 0, stream>>>(pval, psec, pidx, idx, flag);
            else {
                // batch-0 merge must happen before S is overwritten: use z=0-only
                // argred via the same kernel (full 2*NPIX grid is idempotent per t,
                // but batch-1 partials aren't ready) -> do a dedicated pass below.
            }
            if (b == 0) {
                // merge + fix for batch 0 while its S is live
                k_argred<<<18, 256, 0, stream>>>(pval, psec, pidx, idx, flag); // batch1 half garbage, overwritten later
                k_fix2<<<dim3(576, 1), 256, 0, stream>>>(qp, kp, S, invNk, pval, psec,
                                                         pidx, flag, idx, 0L, 0);
            } else {
                k_fix2<<<dim3(576, 1), 256, 0, stream>>>(qp, kp, S, invNk, pval, psec,
                                                         pidx, flag, idx, 0L, 1);
            }
        }
    }
    k_soff<<<(2 * NPIX + 255) / 256, 256, 0, stream>>>(idx, soff);
    k_out2<<<dim3(50, 16), 256, 0, stream>>>(x3, soff, out);
}

// Round 12
// 179.665 us; speedup vs baseline: 1.4232x; 1.0317x over previous
//
#include <hip/hip_runtime.h>
#include <math.h>
#include <float.h>

#define NPIX 2304   // 48*48
#define NPAD 2500   // 50*50
#define PLANE 573440  // 2560*224 padded [p][d] fp32 plane per batch
#define MARGIN 3e-4f

// ws layout in floats
#define OFF_QP     0u         // [2][2560][224] fp32
#define OFF_KP     1146880u   // [2][2560][224] fp32
#define OFF_PLANES 2293760u   // 4 bf16 planes x 2 batches, blocked+swizzled (see k_qk)
#define OFF_NK     4587520u   // [2][2500]
#define OFF_INVNK  4592520u   // [2][2304]
#define OFF_PVAL   4597128u   // [2][48][2304]
#define OFF_PSEC   4818312u   // [2][48][2304]
#define OFF_PIDX   5039496u   // int [2][48][2304]
#define OFF_IDX    5260680u   // int [2][2304]
#define OFF_FLAG   5265288u   // int [2][2304]
#define OFF_S      5269896u   // [z][2500][2500] (2 buffers if ws permits, else 1)
#define OFF_SOFF   OFF_S      // int [2][9][2304] — aliases S (S dead by then)
#define SSTRIDE    6250000L
#define PLANE_SH   573440     // shorts per (plane, batch)

typedef __attribute__((ext_vector_type(8))) short short8;
typedef __attribute__((ext_vector_type(4))) float f32x4;

__device__ __forceinline__ unsigned short bfhi(float f) {
    unsigned u = __float_as_uint(f);
    return (unsigned short)((u + 0x7FFFu + ((u >> 16) & 1u)) >> 16);
}

__device__ __forceinline__ void gload_lds16(const void* g, void* l) {
    __builtin_amdgcn_global_load_lds(
        (const __attribute__((address_space(1))) unsigned int*)g,
        (__attribute__((address_space(3))) unsigned int*)l, 16, 0, 0);
}

// ---- fast zero (rocclr fill is latency-bound; this hits BW) ----
__global__ __launch_bounds__(256) void k_zero(float4* __restrict__ p, int n4) {
    int i = blockIdx.x * 256 + threadIdx.x;
    const int stride = gridDim.x * 256;
    const float4 z = { 0.f, 0.f, 0.f, 0.f };
    for (; i < n4; i += stride) p[i] = z;
}

// ---- stage 1: q = W*x1, k = W*x2 -> fp32 [p][d] rows + bf16 hi/lo blocked planes ----
// bf16 plane layout (per plane, per batch): [panel P 0..19][chunk c 0..6][512 granules]
// granule = 8 bf16 = 16B; logical (row r, d-quad q) at granule G = r*4 + ((q+(r>>1))&3)
// -> frag reads hit the 8-cycle LDS floor; global_load_lds (linear lane*16B dest)
// reproduces this layout in LDS verbatim.
__global__ __launch_bounds__(256) void k_qk(const float* __restrict__ x1,
                                            const float* __restrict__ x2,
                                            const float* __restrict__ W,
                                            float* __restrict__ qp,
                                            float* __restrict__ kp,
                                            unsigned short* __restrict__ planes) {
    __shared__ float Ws[512];
    const int t = threadIdx.x;
    Ws[t] = W[t];
    Ws[t + 256] = W[t + 256];
    __syncthreads();
    const int img = blockIdx.x / 9;      // 0..49  (b*25 + a)
    const int chunk = blockIdx.x % 9;
    const int pix = chunk * 256 + t;     // 0..2303
    const int b = img / 25, a = img % 25;
    const int y = pix / 48, x = pix % 48;

    float q[8], k[8];
#pragma unroll
    for (int o = 0; o < 8; ++o) { q[o] = 0.f; k[o] = 0.f; }

    const float* p1 = x1 + (size_t)b * 64 * 57600 + a * 2304 + pix;
    const float* p2 = x2 + (size_t)b * 64 * 57600 + a * 2304 + pix;
    for (int c = 0; c < 64; ++c) {
        float v1 = p1[c * 57600];
        float v2 = p2[c * 57600];
#pragma unroll
        for (int o = 0; o < 8; ++o) {
            float w = Ws[o * 64 + c];
            q[o] = fmaf(w, v1, q[o]);
            k[o] = fmaf(w, v2, k[o]);
        }
    }
    const int p = (y + 1) * 50 + (x + 1);
    float* qd = qp + (size_t)b * PLANE + (size_t)p * 224 + a * 8;
    float* kd = kp + (size_t)b * PLANE + (size_t)p * 224 + a * 8;
    float4 q0 = { q[0], q[1], q[2], q[3] }, q1 = { q[4], q[5], q[6], q[7] };
    float4 k0 = { k[0], k[1], k[2], k[3] }, k1 = { k[4], k[5], k[6], k[7] };
    *(float4*)qd = q0; *(float4*)(qd + 4) = q1;
    *(float4*)kd = k0; *(float4*)(kd + 4) = k1;

    // bf16 hi/lo granules
    const int P = p >> 7, r = p & 127, cc = a >> 2, dq = a & 3;
    const int g = r * 4 + ((dq + (r >> 1)) & 3);
    const size_t goff = ((size_t)(P * 7 + cc) * 512 + g) * 8;
    short8 qh, ql, kh, kl;
#pragma unroll
    for (int o = 0; o < 8; ++o) {
        unsigned short h = bfhi(q[o]);
        qh[o] = (short)h;
        ql[o] = (short)bfhi(q[o] - __uint_as_float(((unsigned)h) << 16));
        h = bfhi(k[o]);
        kh[o] = (short)h;
        kl[o] = (short)bfhi(k[o] - __uint_as_float(((unsigned)h) << 16));
    }
    *(short8*)(planes + (size_t)(0 * 2 + b) * PLANE_SH + goff) = qh;
    *(short8*)(planes + (size_t)(1 * 2 + b) * PLANE_SH + goff) = ql;
    *(short8*)(planes + (size_t)(2 * 2 + b) * PLANE_SH + goff) = kh;
    *(short8*)(planes + (size_t)(3 * 2 + b) * PLANE_SH + goff) = kl;
}

// ---------------- per-position squared norms of k ----------------
__global__ void k_nk(const float* __restrict__ kp, float* __restrict__ nk) {
    int t = blockIdx.x * 256 + threadIdx.x;  // 0..4999
    if (t >= 2 * NPAD) return;
    int b = t / NPAD, p = t - b * NPAD;
    const float* src = kp + (size_t)b * PLANE + (size_t)p * 224;
    float s = 0.f;
    for (int d = 0; d < 200; d += 4) {
        float4 v = *(const float4*)(src + d);
        s = fmaf(v.x, v.x, s); s = fmaf(v.y, v.y, s);
        s = fmaf(v.z, v.z, s); s = fmaf(v.w, v.w, s);
    }
    nk[t] = s;
}

__global__ void k_invnk(const float* __restrict__ nk, float* __restrict__ invNk) {
    int t = blockIdx.x * 256 + threadIdx.x;  // 0..4607
    if (t >= 2 * NPIX) return;
    int b = t / NPIX, m = t - b * NPIX;
    int my = m / 48, mx = m % 48;
    const float* nb = nk + b * NPAD;
    float s = 0.f;
#pragma unroll
    for (int i = 0; i < 3; ++i)
#pragma unroll
        for (int j = 0; j < 3; ++j)
            s += nb[(my + i) * 50 + mx + j];
    invNk[t] = 1.0f / fmaxf(sqrtf(s), 1e-12f);
}

// ---- stage 2a: S ~= A^T B, 3-term bf16 split, global_load_lds staging ----
__global__ __launch_bounds__(256, 2) void k_mfma2(const unsigned short* __restrict__ planes,
                                                  float* __restrict__ S,
                                                  long sStride, int bofs) {
    __shared__ unsigned short Abuf[2][4096];   // 128 rows x 32 d bf16, swizzled granules
    __shared__ unsigned short Bbuf[2][4096];
    const int t = threadIdx.x;
    const int nwg = gridDim.x * gridDim.y * gridDim.z;   // 400 or 800, %8==0
    const int lin = (blockIdx.z * gridDim.y + blockIdx.y) * gridDim.x + blockIdx.x;
    const int work = (lin & 7) * (nwg >> 3) + (lin >> 3);
    const int z = work / 400;
    const int rem = work - z * 400;
    const int wy = rem / 20, wx = rem - (rem / 20) * 20;
    const int b = bofs + z;

    const unsigned short* Ahi = planes + (size_t)(0 * 2 + b) * PLANE_SH;
    const unsigned short* Alo = planes + (size_t)(1 * 2 + b) * PLANE_SH;
    const unsigned short* Bhi = planes + (size_t)(2 * 2 + b) * PLANE_SH;
    const unsigned short* Blo = planes + (size_t)(3 * 2 + b) * PLANE_SH;
    float* Sb = S + (size_t)z * sStride;

    const int p0 = wy * 128, r0 = wx * 128;
    const int wid = t >> 6, l = t & 63;
    const int lp = l & 15, dq = l >> 4;
    const int wqp = (wid >> 1) * 64, wqr = (wid & 1) * 64;

    // loop-invariant frag LDS offsets (shorts)
    int aoff[4], boff[4];
#pragma unroll
    for (int tr = 0; tr < 4; ++tr) {
        int rA = wqp + tr * 16 + lp;
        aoff[tr] = (rA * 4 + ((dq + (rA >> 1)) & 3)) * 8;
        int rB = wqr + tr * 16 + lp;
        boff[tr] = (rB * 4 + ((dq + (rB >> 1)) & 3)) * 8;
    }

    f32x4 acc[4][4];
#pragma unroll
    for (int i = 0; i < 4; ++i)
#pragma unroll
        for (int j = 0; j < 4; ++j) acc[i][j] = (f32x4){0.f, 0.f, 0.f, 0.f};

#define STAGE(buf, ks)                                                          \
    {                                                                           \
        const int term = (ks) / 7, c = (ks) - term * 7;                         \
        const unsigned short* gA = (term < 2 ? Ahi : Alo) + ((size_t)(wy * 7 + c) << 12); \
        const unsigned short* gB = (term != 1 ? Bhi : Blo) + ((size_t)(wx * 7 + c) << 12); \
        unsigned short* lA = &Abuf[buf][wid * 512];                             \
        unsigned short* lB = &Bbuf[buf][wid * 512];                             \
        gload_lds16(gA + t * 8, lA);                                            \
        gload_lds16(gA + 2048 + t * 8, lA + 2048);                              \
        gload_lds16(gB + t * 8, lB);                                            \
        gload_lds16(gB + 2048 + t * 8, lB + 2048);                              \
    }

    STAGE(0, 0);
    asm volatile("s_waitcnt vmcnt(0)" ::: "memory");
    __syncthreads();

    int cur = 0;
    for (int ks = 0; ks < 21; ++ks) {
        if (ks + 1 < 21) STAGE(cur ^ 1, ks + 1);
        {
            const unsigned short* Ab = &Abuf[cur][0];
            const unsigned short* Bb = &Bbuf[cur][0];
            short8 af[4], bfr[4];
#pragma unroll
            for (int tr = 0; tr < 4; ++tr) af[tr] = *(const short8*)(Ab + aoff[tr]);
#pragma unroll
            for (int tc = 0; tc < 4; ++tc) bfr[tc] = *(const short8*)(Bb + boff[tc]);
#pragma unroll
            for (int tr = 0; tr < 4; ++tr)
#pragma unroll
                for (int tc = 0; tc < 4; ++tc)
                    acc[tr][tc] = __builtin_amdgcn_mfma_f32_16x16x32_bf16(
                        af[tr], bfr[tc], acc[tr][tc], 0, 0, 0);
        }
        if (ks + 1 < 21) {
            asm volatile("s_waitcnt vmcnt(0)" ::: "memory");
            __syncthreads();
            cur ^= 1;
        }
    }
#undef STAGE

    // D mapping (R8-verified): per 16x16 tile, row = dq*4 + v, col = lp
#pragma unroll
    for (int tr = 0; tr < 4; ++tr) {
#pragma unroll
        for (int v = 0; v < 4; ++v) {
            const int p = p0 + wqp + tr * 16 + dq * 4 + v;
            if (p < NPAD) {
                float* srow_ = Sb + (size_t)p * NPAD;
#pragma unroll
                for (int tc = 0; tc < 4; ++tc) {
                    const int c = r0 + wqr + tc * 16 + lp;
                    if (c < NPAD) srow_[c] = acc[tr][tc][v];
                }
            }
        }
    }
}

// -------- stage 2b: block per (my, ly, z); box-sum + partial top-2 argmax --------
// R11 rewrite: divide-free float2 band load; imm-offset box-sum reads.
__global__ __launch_bounds__(384) void k_argmax(const float* __restrict__ S,
                                                const float* __restrict__ invNk,
                                                float* __restrict__ pval,
                                                float* __restrict__ psec,
                                                int* __restrict__ pidx,
                                                long sStride, int bofs) {
    __shared__ float band[3][50][50];
    const int t = threadIdx.x;
    const int my = blockIdx.x;     // 0..47
    const int ly = blockIdx.y;     // 0..47
    const int batch = bofs + blockIdx.z;
    const float* Sb = S + (size_t)blockIdx.z * sStride;

    // band load: 150 rows x 50 floats, 8 lanes/row, float2 — no per-element divides
    {
        const int rt = t >> 3, ct = t & 7;
        for (int rr = rt; rr < 150; rr += 48) {
            const int i = (rr >= 100) ? 2 : (rr >= 50 ? 1 : 0);
            const int uu = rr - i * 50;
            const float* srow = Sb + (size_t)((ly + i) * 50 + uu) * NPAD + (my + i) * 50;
            float* drow = &band[i][uu][0];
            *(float2*)(drow + 2 * ct)      = *(const float2*)(srow + 2 * ct);
            *(float2*)(drow + 16 + 2 * ct) = *(const float2*)(srow + 16 + 2 * ct);
            *(float2*)(drow + 32 + 2 * ct) = *(const float2*)(srow + 32 + 2 * ct);
            if (ct == 0) *(float2*)(drow + 48) = *(const float2*)(srow + 48);
        }
    }
    __syncthreads();

    const int lx = t >> 3;         // 0..47
    const int mc = t & 7;          // 0..7
    const float* inb = invNk + batch * NPIX;
    // thread base; all 9 taps are loop-invariant offsets -> ds_read offset:imm
    const float* bp = &band[0][lx][mc];

    float b1 = -FLT_MAX, b2 = -FLT_MAX;
    int i1 = 0x7FFFFFFF;

#pragma unroll
    for (int k = 0; k < 6; ++k) {
        const float* p = bp + 8 * k;
        float s = p[0]    + p[51]   + p[102]      // i=0, j=0..2 (51 = 50+1 diag)
                + p[2500] + p[2551] + p[2602]     // i=1
                + p[5000] + p[5051] + p[5102];    // i=2
        int m = my * 48 + mc + (k << 3);
        float v = s * inb[m];
        if (v > b1 || (v == b1 && m < i1)) { b2 = b1; b1 = v; i1 = m; }
        else b2 = fmaxf(b2, v);
    }
#pragma unroll
    for (int off = 1; off < 8; off <<= 1) {
        float ob1 = __shfl_xor(b1, off, 64);
        int oi1 = __shfl_xor(i1, off, 64);
        float ob2 = __shfl_xor(b2, off, 64);
        if (ob1 > b1 || (ob1 == b1 && oi1 < i1)) { b2 = fmaxf(b1, ob2); b1 = ob1; i1 = oi1; }
        else b2 = fmaxf(b2, ob1);
    }
    if (mc == 0) {
        int o = (batch * 48 + my) * NPIX + ly * 48 + lx;
        pval[o] = b1;
        psec[o] = b2;
        pidx[o] = i1;
    }
}

// merge over my partials (both batches in one launch)
__global__ void k_argred(const float* __restrict__ pval, const float* __restrict__ psec,
                         const int* __restrict__ pidx, int* __restrict__ idxout,
                         int* __restrict__ flag) {
    int t = blockIdx.x * 256 + threadIdx.x;
    if (t >= 2 * NPIX) return;
    int b = t / NPIX, lcl = t - b * NPIX;
    float b1 = -FLT_MAX, b2 = -FLT_MAX;
    int i1 = 0x7FFFFFFF;
    for (int my = 0; my < 48; ++my) {
        int o = (b * 48 + my) * NPIX + lcl;
        float v1 = pval[o], v2 = psec[o];
        int ii = pidx[o];
        if (v1 > b1 || (v1 == b1 && ii < i1)) { b2 = fmaxf(b1, v2); b1 = v1; i1 = ii; }
        else b2 = fmaxf(b2, v1);
    }
    idxout[t] = i1;
    flag[t] = (b1 - b2 < MARGIN) ? 1 : 0;
}

// -------- candidate-pruned exact recheck: one wave per flagged row --------
__global__ __launch_bounds__(256) void k_fix2(const float* __restrict__ qp,
                                              const float* __restrict__ kp,
                                              const float* __restrict__ S,
                                              const float* __restrict__ invNk,
                                              const float* __restrict__ pval,
                                              const float* __restrict__ psec,
                                              const int* __restrict__ pidx,
                                              const int* __restrict__ flag,
                                              int* __restrict__ idx,
                                              long sStride, int bofs) {
    const int t = threadIdx.x;
    const int lane = t & 63;
    const int row = blockIdx.x * 4 + (t >> 6);
    const int z = blockIdx.y;
    const int b = bofs + z;
    if (!flag[b * NPIX + row]) return;
    const float* Sb = S + (size_t)z * sStride;
    const float* Ap = qp + (size_t)b * PLANE;
    const float* Bp = kp + (size_t)b * PLANE;
    const float* inb = invNk + b * NPIX;
    const int ly = row / 48, lx = row % 48;

    float v1 = -FLT_MAX, v2 = -FLT_MAX;
    if (lane < 48) {
        int o = (b * 48 + lane) * NPIX + row;
        v1 = pval[o];
        v2 = psec[o];
    }
    float bb = v1;
#pragma unroll
    for (int off = 1; off < 64; off <<= 1)
        bb = fmaxf(bb, __shfl_xor(bb, off, 64));
    const float th = bb - MARGIN;

    unsigned long long mask = __ballot(lane < 48 && (v1 >= th || v2 >= th));
    float eb = -FLT_MAX;
    int ebi = 0x7FFFFFFF;
    while (mask) {
        const int my = __ffsll((long long)mask) - 1;
        mask &= mask - 1;
        float va = -FLT_MAX;
        if (lane < 48) {
            float s = 0.f;
#pragma unroll
            for (int i = 0; i < 3; ++i)
#pragma unroll
                for (int j = 0; j < 3; ++j)
                    s += Sb[(size_t)((ly + i) * 50 + lx + j) * NPAD + (my + i) * 50 + lane + j];
            va = s * inb[my * 48 + lane];
        }
        unsigned long long m2 = __ballot(lane < 48 && va >= th);
        while (m2) {
            const int mx = __ffsll((long long)m2) - 1;
            m2 &= m2 - 1;
            const int m = my * 48 + mx;
            float part = 0.f;
#pragma unroll
            for (int ij = 0; ij < 9; ++ij) {
                const float* qr = Ap + (size_t)((ly + ij / 3) * 50 + lx + ij % 3) * 224;
                const float* kr = Bp + (size_t)((my + ij / 3) * 50 + mx + ij % 3) * 224;
                for (int d = lane; d < 200; d += 64)
                    part = fmaf(qr[d], kr[d], part);
            }
#pragma unroll
            for (int off = 1; off < 64; off <<= 1)
                part += __shfl_xor(part, off, 64);
            const float v = part * inb[m];
            if (v > eb) { eb = v; ebi = m; }
        }
    }
    if (lane == 0 && ebi != 0x7FFFFFFF) idx[b * NPIX + row] = ebi;
}

// ---------------- stage 3a: per-(b,pixel) 9 source offsets ----------------
__global__ void k_soff(const int* __restrict__ idx, int* __restrict__ soff) {
    int t = blockIdx.x * 256 + threadIdx.x;
    if (t >= 2 * NPIX) return;
    int b = t / NPIX, pix = t - b * NPIX;
    int y = pix / 48, x = pix % 48;
#pragma unroll
    for (int i = 0; i < 3; ++i) {
#pragma unroll
        for (int j = 0; j < 3; ++j) {
            int u = i * 3 + j;
            int yq = y + 1 - i, xq = x + 1 - j;
            int so = -1;
            if (yq >= 0 && yq < 48 && xq >= 0 && xq < 48) {
                int m = idx[b * NPIX + yq * 48 + xq];
                int my = m / 48, mx = m % 48;
                int yy = my + i - 1, xx = mx + j - 1;
                if (yy >= 0 && yy < 48 && xx >= 0 && xx < 48) so = yy * 48 + xx;
            }
            soff[(b * 9 + u) * NPIX + pix] = so;
        }
    }
}

// ---------------- stage 3b: gather + fold via LDS-staged plane ----------------
#define CPB 4
__global__ __launch_bounds__(256) void k_out2(const float* __restrict__ x3,
                                              const int* __restrict__ soff,
                                              float* __restrict__ out) {
    __shared__ __align__(16) float plane[NPIX];
    const int t = threadIdx.x;
    const int img = blockIdx.x;
    const int b = img / 25, a = img % 25;

    int po[9][9];
#pragma unroll
    for (int u = 0; u < 9; ++u) {
        const int* sb = soff + (b * 9 + u) * NPIX;
#pragma unroll
        for (int k = 0; k < 9; ++k)
            po[k][u] = sb[k * 256 + t];
    }

    const size_t pbase = (size_t)b * 64 * 57600 + (size_t)a * 2304 +
                         (size_t)(blockIdx.y * CPB) * 57600;
    const float* gsrc = x3 + pbase;
    float* gdst = out + pbase;

    float4 r0, r1, r2;
    {
        const float4* g = (const float4*)gsrc;
        r0 = g[t]; r1 = g[t + 256];
        if (t < 64) r2 = g[t + 512];
    }
    float4* pl4 = (float4*)plane;
    pl4[t] = r0; pl4[t + 256] = r1;
    if (t < 64) pl4[t + 512] = r2;
    __syncthreads();

    for (int c = 0; c < CPB; ++c) {
        if (c + 1 < CPB) {
            const float4* g = (const float4*)(gsrc + (size_t)(c + 1) * 57600);
            r0 = g[t]; r1 = g[t + 256];
            if (t < 64) r2 = g[t + 512];
        }
        float* dst = gdst + (size_t)c * 57600;
#pragma unroll
        for (int k = 0; k < 9; ++k) {
            float acc = 0.f;
#pragma unroll
            for (int u = 0; u < 9; ++u) {
                int off = po[k][u];
                int ao = off < 0 ? 0 : off;
                float v = plane[ao];
                acc += (off < 0) ? 0.f : v;
            }
            dst[k * 256 + t] = acc;
        }
        __syncthreads();
        if (c + 1 < CPB) {
            pl4[t] = r0; pl4[t + 256] = r1;
            if (t < 64) pl4[t + 512] = r2;
        }
        __syncthreads();
    }
}

extern "C" void kernel_launch(void* const* d_in, const int* in_sizes, int n_in,
                              void* d_out, int out_size, void* d_ws, size_t ws_size,
                              hipStream_t stream) {
    const float* x1 = (const float*)d_in[0];
    const float* x2 = (const float*)d_in[1];
    const float* x3 = (const float*)d_in[2];
    const float* W  = (const float*)d_in[3];
    float* ws = (float*)d_ws;

    float* qp    = ws + OFF_QP;
    float* kp    = ws + OFF_KP;
    unsigned short* planes = (unsigned short*)(ws + OFF_PLANES);
    float* nk    = ws + OFF_NK;
    float* invNk = ws + OFF_INVNK;
    float* pval  = ws + OFF_PVAL;
    float* psec  = ws + OFF_PSEC;
    int*   pidx  = (int*)(ws + OFF_PIDX);
    int*   idx   = (int*)(ws + OFF_IDX);
    int*   flag  = (int*)(ws + OFF_FLAG);
    float* S     = ws + OFF_S;
    int*   soff  = (int*)(ws + OFF_SOFF);
    float* out   = (float*)d_out;

    const bool bigS = ws_size >= (size_t)(OFF_S + 2UL * (unsigned long)SSTRIDE) * 4UL;

    // zero qp/kp/planes (padding) — custom kernel, not latency-bound rocclr fill
    k_zero<<<2048, 256, 0, stream>>>((float4*)(ws + OFF_QP), (int)(OFF_NK / 4));

    k_qk<<<450, 256, 0, stream>>>(x1, x2, W, qp, kp, planes);
    k_nk<<<(2 * NPAD + 255) / 256, 256, 0, stream>>>(kp, nk);
    k_invnk<<<(2 * NPIX + 255) / 256, 256, 0, stream>>>(nk, invNk);

    if (bigS) {
        k_mfma2<<<dim3(20, 20, 2), 256, 0, stream>>>(planes, S, SSTRIDE, 0);
        k_argmax<<<dim3(48, 48, 2), 384, 0, stream>>>(S, invNk, pval, psec, pidx, SSTRIDE, 0);
        k_argred<<<18, 256, 0, stream>>>(pval, psec, pidx, idx, flag);
        k_fix2<<<dim3(576, 2), 256, 0, stream>>>(qp, kp, S, invNk, pval, psec, pidx,
                                                 flag, idx, SSTRIDE, 0);
    } else {
        for (int b = 0; b < 2; ++b) {
            k_mfma2<<<dim3(20, 20, 1), 256, 0, stream>>>(planes, S, 0L, b);
            k_argmax<<<dim3(48, 48, 1), 384, 0, stream>>>(S, invNk, pval, psec, pidx, 0L, b);
            k_argred<<<18, 256, 0, stream>>>(pval, psec, pidx, idx, flag);
            k_fix2<<<dim3(576, 1), 256, 0, stream>>>(qp, kp, S, invNk, pval, psec,
                                                     pidx, flag, idx, 0L, b);
        }
    }
    k_soff<<<(2 * NPIX + 255) / 256, 256, 0, stream>>>(idx, soff);
    k_out2<<<dim3(50, 16), 256, 0, stream>>>(x3, soff, out);
}

// Round 13
// 147.456 us; speedup vs baseline: 1.7341x; 1.2184x over previous
//
#include <hip/hip_runtime.h>
#include <math.h>
#include <float.h>

#define NPIX 2304   // 48*48
#define NPAD 2500   // 50*50
#define PLANE 573440  // 2560*224 padded [p][d] fp32 plane per batch
#define MARGIN 3e-4f

// ws layout in floats
#define OFF_QP     0u         // [2][2560][224] fp32
#define OFF_KP     1146880u   // [2][2560][224] fp32
#define OFF_PLANES 2293760u   // 4 bf16 planes x 2 batches, blocked+swizzled (see k_qk)
#define OFF_NK     4587520u   // [2][2500]
#define OFF_INVNK  4592520u   // [2][2304]
#define OFF_PVAL   4597128u   // [2][48][2304]
#define OFF_PSEC   4818312u   // [2][48][2304]
#define OFF_PIDX   5039496u   // int [2][48][2304]
#define OFF_IDX    5260680u   // int [2][2304]
#define OFF_S      5269896u   // [z][2500][2500] (2 buffers if ws permits, else 1)
#define OFF_SOFF   OFF_S      // int [2][9][2304] — aliases S (S dead by then)
#define SSTRIDE    6250000L
#define PLANE_SH   573440     // shorts per (plane, batch)

typedef __attribute__((ext_vector_type(8))) short short8;
typedef __attribute__((ext_vector_type(4))) float f32x4;

__device__ __forceinline__ unsigned short bfhi(float f) {
    unsigned u = __float_as_uint(f);
    return (unsigned short)((u + 0x7FFFu + ((u >> 16) & 1u)) >> 16);
}

__device__ __forceinline__ void gload_lds16(const void* g, void* l) {
    __builtin_amdgcn_global_load_lds(
        (const __attribute__((address_space(1))) unsigned int*)g,
        (__attribute__((address_space(3))) unsigned int*)l, 16, 0, 0);
}

// ---- fast zero (rocclr fill is latency-bound; this hits BW) ----
__global__ __launch_bounds__(256) void k_zero(float4* __restrict__ p, int n4) {
    int i = blockIdx.x * 256 + threadIdx.x;
    const int stride = gridDim.x * 256;
    const float4 z = { 0.f, 0.f, 0.f, 0.f };
    for (; i < n4; i += stride) p[i] = z;
}

// ---- stage 1: q = W*x1, k = W*x2 -> fp32 [p][d] rows + bf16 hi/lo blocked planes ----
// bf16 plane layout (per plane, per batch): [panel P 0..19][chunk c 0..6][512 granules]
// granule = 8 bf16 = 16B; logical (row r, d-quad q) at granule G = r*4 + ((q+(r>>1))&3)
// -> frag reads hit the 8-cycle LDS floor; global_load_lds (linear lane*16B dest)
// reproduces this layout in LDS verbatim.
__global__ __launch_bounds__(256) void k_qk(const float* __restrict__ x1,
                                            const float* __restrict__ x2,
                                            const float* __restrict__ W,
                                            float* __restrict__ qp,
                                            float* __restrict__ kp,
                                            unsigned short* __restrict__ planes) {
    __shared__ float Ws[512];
    const int t = threadIdx.x;
    Ws[t] = W[t];
    Ws[t + 256] = W[t + 256];
    __syncthreads();
    const int img = blockIdx.x / 9;      // 0..49  (b*25 + a)
    const int chunk = blockIdx.x % 9;
    const int pix = chunk * 256 + t;     // 0..2303
    const int b = img / 25, a = img % 25;
    const int y = pix / 48, x = pix % 48;

    float q[8], k[8];
#pragma unroll
    for (int o = 0; o < 8; ++o) { q[o] = 0.f; k[o] = 0.f; }

    const float* p1 = x1 + (size_t)b * 64 * 57600 + a * 2304 + pix;
    const float* p2 = x2 + (size_t)b * 64 * 57600 + a * 2304 + pix;
#pragma unroll 8
    for (int c = 0; c < 64; ++c) {
        float v1 = p1[c * 57600];
        float v2 = p2[c * 57600];
#pragma unroll
        for (int o = 0; o < 8; ++o) {
            float w = Ws[o * 64 + c];
            q[o] = fmaf(w, v1, q[o]);
            k[o] = fmaf(w, v2, k[o]);
        }
    }
    const int p = (y + 1) * 50 + (x + 1);
    float* qd = qp + (size_t)b * PLANE + (size_t)p * 224 + a * 8;
    float* kd = kp + (size_t)b * PLANE + (size_t)p * 224 + a * 8;
    float4 q0 = { q[0], q[1], q[2], q[3] }, q1 = { q[4], q[5], q[6], q[7] };
    float4 k0 = { k[0], k[1], k[2], k[3] }, k1 = { k[4], k[5], k[6], k[7] };
    *(float4*)qd = q0; *(float4*)(qd + 4) = q1;
    *(float4*)kd = k0; *(float4*)(kd + 4) = k1;

    // bf16 hi/lo granules
    const int P = p >> 7, r = p & 127, cc = a >> 2, dq = a & 3;
    const int g = r * 4 + ((dq + (r >> 1)) & 3);
    const size_t goff = ((size_t)(P * 7 + cc) * 512 + g) * 8;
    short8 qh, ql, kh, kl;
#pragma unroll
    for (int o = 0; o < 8; ++o) {
        unsigned short h = bfhi(q[o]);
        qh[o] = (short)h;
        ql[o] = (short)bfhi(q[o] - __uint_as_float(((unsigned)h) << 16));
        h = bfhi(k[o]);
        kh[o] = (short)h;
        kl[o] = (short)bfhi(k[o] - __uint_as_float(((unsigned)h) << 16));
    }
    *(short8*)(planes + (size_t)(0 * 2 + b) * PLANE_SH + goff) = qh;
    *(short8*)(planes + (size_t)(1 * 2 + b) * PLANE_SH + goff) = ql;
    *(short8*)(planes + (size_t)(2 * 2 + b) * PLANE_SH + goff) = kh;
    *(short8*)(planes + (size_t)(3 * 2 + b) * PLANE_SH + goff) = kl;
}

// ---------------- per-position squared norms of k ----------------
__global__ void k_nk(const float* __restrict__ kp, float* __restrict__ nk) {
    int t = blockIdx.x * 256 + threadIdx.x;  // 0..4999
    if (t >= 2 * NPAD) return;
    int b = t / NPAD, p = t - b * NPAD;
    const float* src = kp + (size_t)b * PLANE + (size_t)p * 224;
    float s = 0.f;
    for (int d = 0; d < 200; d += 4) {
        float4 v = *(const float4*)(src + d);
        s = fmaf(v.x, v.x, s); s = fmaf(v.y, v.y, s);
        s = fmaf(v.z, v.z, s); s = fmaf(v.w, v.w, s);
    }
    nk[t] = s;
}

__global__ void k_invnk(const float* __restrict__ nk, float* __restrict__ invNk) {
    int t = blockIdx.x * 256 + threadIdx.x;  // 0..4607
    if (t >= 2 * NPIX) return;
    int b = t / NPIX, m = t - b * NPIX;
    int my = m / 48, mx = m % 48;
    const float* nb = nk + b * NPAD;
    float s = 0.f;
#pragma unroll
    for (int i = 0; i < 3; ++i)
#pragma unroll
        for (int j = 0; j < 3; ++j)
            s += nb[(my + i) * 50 + mx + j];
    invNk[t] = 1.0f / fmaxf(sqrtf(s), 1e-12f);
}

// ---- stage 2a: S ~= A^T B, 3-term bf16 split, global_load_lds staging ----
__global__ __launch_bounds__(256, 2) void k_mfma2(const unsigned short* __restrict__ planes,
                                                  float* __restrict__ S,
                                                  long sStride, int bofs) {
    __shared__ unsigned short Abuf[2][4096];   // 128 rows x 32 d bf16, swizzled granules
    __shared__ unsigned short Bbuf[2][4096];
    const int t = threadIdx.x;
    const int nwg = gridDim.x * gridDim.y * gridDim.z;   // 400 or 800, %8==0
    const int lin = (blockIdx.z * gridDim.y + blockIdx.y) * gridDim.x + blockIdx.x;
    const int work = (lin & 7) * (nwg >> 3) + (lin >> 3);
    const int z = work / 400;
    const int rem = work - z * 400;
    const int wy = rem / 20, wx = rem - (rem / 20) * 20;
    const int b = bofs + z;

    const unsigned short* Ahi = planes + (size_t)(0 * 2 + b) * PLANE_SH;
    const unsigned short* Alo = planes + (size_t)(1 * 2 + b) * PLANE_SH;
    const unsigned short* Bhi = planes + (size_t)(2 * 2 + b) * PLANE_SH;
    const unsigned short* Blo = planes + (size_t)(3 * 2 + b) * PLANE_SH;
    float* Sb = S + (size_t)z * sStride;

    const int p0 = wy * 128, r0 = wx * 128;
    const int wid = t >> 6, l = t & 63;
    const int lp = l & 15, dq = l >> 4;
    const int wqp = (wid >> 1) * 64, wqr = (wid & 1) * 64;

    // loop-invariant frag LDS offsets (shorts)
    int aoff[4], boff[4];
#pragma unroll
    for (int tr = 0; tr < 4; ++tr) {
        int rA = wqp + tr * 16 + lp;
        aoff[tr] = (rA * 4 + ((dq + (rA >> 1)) & 3)) * 8;
        int rB = wqr + tr * 16 + lp;
        boff[tr] = (rB * 4 + ((dq + (rB >> 1)) & 3)) * 8;
    }

    f32x4 acc[4][4];
#pragma unroll
    for (int i = 0; i < 4; ++i)
#pragma unroll
        for (int j = 0; j < 4; ++j) acc[i][j] = (f32x4){0.f, 0.f, 0.f, 0.f};

#define STAGE(buf, ks)                                                          \
    {                                                                           \
        const int term = (ks) / 7, c = (ks) - term * 7;                         \
        const unsigned short* gA = (term < 2 ? Ahi : Alo) + ((size_t)(wy * 7 + c) << 12); \
        const unsigned short* gB = (term != 1 ? Bhi : Blo) + ((size_t)(wx * 7 + c) << 12); \
        unsigned short* lA = &Abuf[buf][wid * 512];                             \
        unsigned short* lB = &Bbuf[buf][wid * 512];                             \
        gload_lds16(gA + t * 8, lA);                                            \
        gload_lds16(gA + 2048 + t * 8, lA + 2048);                              \
        gload_lds16(gB + t * 8, lB);                                            \
        gload_lds16(gB + 2048 + t * 8, lB + 2048);                              \
    }

    STAGE(0, 0);
    asm volatile("s_waitcnt vmcnt(0)" ::: "memory");
    __syncthreads();

    int cur = 0;
    for (int ks = 0; ks < 21; ++ks) {
        if (ks + 1 < 21) STAGE(cur ^ 1, ks + 1);
        {
            const unsigned short* Ab = &Abuf[cur][0];
            const unsigned short* Bb = &Bbuf[cur][0];
            short8 af[4], bfr[4];
#pragma unroll
            for (int tr = 0; tr < 4; ++tr) af[tr] = *(const short8*)(Ab + aoff[tr]);
#pragma unroll
            for (int tc = 0; tc < 4; ++tc) bfr[tc] = *(const short8*)(Bb + boff[tc]);
#pragma unroll
            for (int tr = 0; tr < 4; ++tr)
#pragma unroll
                for (int tc = 0; tc < 4; ++tc)
                    acc[tr][tc] = __builtin_amdgcn_mfma_f32_16x16x32_bf16(
                        af[tr], bfr[tc], acc[tr][tc], 0, 0, 0);
        }
        if (ks + 1 < 21) {
            asm volatile("s_waitcnt vmcnt(0)" ::: "memory");
            __syncthreads();
            cur ^= 1;
        }
    }
#undef STAGE

    // D mapping (R8-verified): per 16x16 tile, row = dq*4 + v, col = lp
#pragma unroll
    for (int tr = 0; tr < 4; ++tr) {
#pragma unroll
        for (int v = 0; v < 4; ++v) {
            const int p = p0 + wqp + tr * 16 + dq * 4 + v;
            if (p < NPAD) {
                float* srow_ = Sb + (size_t)p * NPAD;
#pragma unroll
                for (int tc = 0; tc < 4; ++tc) {
                    const int c = r0 + wqr + tc * 16 + lp;
                    if (c < NPAD) srow_[c] = acc[tr][tc][v];
                }
            }
        }
    }
}

// -------- stage 2b: box-sum + partial top-2 argmax --------
// XCD-swizzled so each XCD processes contiguous (z,ly) bands: blocks sharing ly
// read the SAME 150 S-rows (1.5 MB) -> L2-resident per XCD instead of refetch.
__global__ __launch_bounds__(384) void k_argmax(const float* __restrict__ S,
                                                const float* __restrict__ invNk,
                                                float* __restrict__ pval,
                                                float* __restrict__ psec,
                                                int* __restrict__ pidx,
                                                long sStride, int bofs) {
    __shared__ float band[3][50][50];
    const int t = threadIdx.x;
    const int nwg = gridDim.x * gridDim.y * gridDim.z;   // 2304 or 4608, %8==0
    const int lin = (blockIdx.z * gridDim.y + blockIdx.y) * gridDim.x + blockIdx.x;
    const int work = (lin & 7) * (nwg >> 3) + (lin >> 3);
    const int z = work / 2304;
    const int w2 = work - z * 2304;
    const int ly = w2 / 48;        // 0..47 (contiguous per XCD)
    const int my = w2 - ly * 48;   // 0..47
    const int batch = bofs + z;
    const float* Sb = S + (size_t)z * sStride;

    // band load: 150 rows x 50 floats, 8 lanes/row, float2 — no per-element divides
    {
        const int rt = t >> 3, ct = t & 7;
        for (int rr = rt; rr < 150; rr += 48) {
            const int i = (rr >= 100) ? 2 : (rr >= 50 ? 1 : 0);
            const int uu = rr - i * 50;
            const float* srow = Sb + (size_t)((ly + i) * 50 + uu) * NPAD + (my + i) * 50;
            float* drow = &band[i][uu][0];
            *(float2*)(drow + 2 * ct)      = *(const float2*)(srow + 2 * ct);
            *(float2*)(drow + 16 + 2 * ct) = *(const float2*)(srow + 16 + 2 * ct);
            *(float2*)(drow + 32 + 2 * ct) = *(const float2*)(srow + 32 + 2 * ct);
            if (ct == 0) *(float2*)(drow + 48) = *(const float2*)(srow + 48);
        }
    }
    __syncthreads();

    const int lx = t >> 3;         // 0..47
    const int mc = t & 7;          // 0..7
    const float* inb = invNk + batch * NPIX;
    const float* bp = &band[0][lx][mc];

    float b1 = -FLT_MAX, b2 = -FLT_MAX;
    int i1 = 0x7FFFFFFF;

#pragma unroll
    for (int k = 0; k < 6; ++k) {
        const float* p = bp + 8 * k;
        float s = p[0]    + p[51]   + p[102]
                + p[2500] + p[2551] + p[2602]
                + p[5000] + p[5051] + p[5102];
        int m = my * 48 + mc + (k << 3);
        float v = s * inb[m];
        if (v > b1 || (v == b1 && m < i1)) { b2 = b1; b1 = v; i1 = m; }
        else b2 = fmaxf(b2, v);
    }
#pragma unroll
    for (int off = 1; off < 8; off <<= 1) {
        float ob1 = __shfl_xor(b1, off, 64);
        int oi1 = __shfl_xor(i1, off, 64);
        float ob2 = __shfl_xor(b2, off, 64);
        if (ob1 > b1 || (ob1 == b1 && oi1 < i1)) { b2 = fmaxf(b1, ob2); b1 = ob1; i1 = oi1; }
        else b2 = fmaxf(b2, ob1);
    }
    if (mc == 0) {
        int o = (batch * 48 + my) * NPIX + ly * 48 + lx;
        pval[o] = b1;
        psec[o] = b2;
        pidx[o] = i1;
    }
}

// -------- merged select: top-2 merge over my partials + exact recheck if close ----
// One wave per row. Butterfly merge is equivalent to the sequential argred merge
// (b2 <= b1 invariant; ties resolve to min index; verified on tie/chain cases).
__global__ __launch_bounds__(256) void k_sel(const float* __restrict__ qp,
                                             const float* __restrict__ kp,
                                             const float* __restrict__ S,
                                             const float* __restrict__ invNk,
                                             const float* __restrict__ pval,
                                             const float* __restrict__ psec,
                                             const int* __restrict__ pidx,
                                             int* __restrict__ idx,
                                             long sStride, int bofs) {
    const int t = threadIdx.x;
    const int lane = t & 63;
    const int row = blockIdx.x * 4 + (t >> 6);
    const int z = blockIdx.y;
    const int b = bofs + z;

    float v1 = -FLT_MAX, v2 = -FLT_MAX;
    int ii = 0x7FFFFFFF;
    if (lane < 48) {
        int o = (b * 48 + lane) * NPIX + row;
        v1 = pval[o];
        v2 = psec[o];
        ii = pidx[o];
    }
    float r1 = v1, r2 = v2;
    int ri = ii;
#pragma unroll
    for (int off = 1; off < 64; off <<= 1) {
        float o1 = __shfl_xor(r1, off, 64);
        int oi = __shfl_xor(ri, off, 64);
        float o2 = __shfl_xor(r2, off, 64);
        if (o1 > r1 || (o1 == r1 && oi < ri)) { r2 = fmaxf(o2, r1); r1 = o1; ri = oi; }
        else r2 = fmaxf(r2, o1);
    }
    if (lane == 0) idx[b * NPIX + row] = ri;
    if (r1 - r2 >= MARGIN) return;

    // close call: candidate-pruned exact recheck
    const float* Sb = S + (size_t)z * sStride;
    const float* Ap = qp + (size_t)b * PLANE;
    const float* Bp = kp + (size_t)b * PLANE;
    const float* inb = invNk + b * NPIX;
    const int ly = row / 48, lx = row % 48;
    const float th = r1 - MARGIN;

    unsigned long long mask = __ballot(lane < 48 && (v1 >= th || v2 >= th));
    float eb = -FLT_MAX;
    int ebi = 0x7FFFFFFF;
    while (mask) {
        const int my = __ffsll((long long)mask) - 1;
        mask &= mask - 1;
        float va = -FLT_MAX;
        if (lane < 48) {
            float s = 0.f;
#pragma unroll
            for (int i = 0; i < 3; ++i)
#pragma unroll
                for (int j = 0; j < 3; ++j)
                    s += Sb[(size_t)((ly + i) * 50 + lx + j) * NPAD + (my + i) * 50 + lane + j];
            va = s * inb[my * 48 + lane];
        }
        unsigned long long m2 = __ballot(lane < 48 && va >= th);
        while (m2) {
            const int mx = __ffsll((long long)m2) - 1;
            m2 &= m2 - 1;
            const int m = my * 48 + mx;
            float part = 0.f;
#pragma unroll
            for (int ij = 0; ij < 9; ++ij) {
                const float* qr = Ap + (size_t)((ly + ij / 3) * 50 + lx + ij % 3) * 224;
                const float* kr = Bp + (size_t)((my + ij / 3) * 50 + mx + ij % 3) * 224;
                for (int d = lane; d < 200; d += 64)
                    part = fmaf(qr[d], kr[d], part);
            }
#pragma unroll
            for (int off = 1; off < 64; off <<= 1)
                part += __shfl_xor(part, off, 64);
            const float v = part * inb[m];
            if (v > eb) { eb = v; ebi = m; }  // ascending m scan -> min-m tie-break
        }
    }
    if (lane == 0 && ebi != 0x7FFFFFFF) idx[b * NPIX + row] = ebi;
}

// ---------------- stage 3a: per-(b,pixel) 9 source offsets ----------------
__global__ void k_soff(const int* __restrict__ idx, int* __restrict__ soff) {
    int t = blockIdx.x * 256 + threadIdx.x;
    if (t >= 2 * NPIX) return;
    int b = t / NPIX, pix = t - b * NPIX;
    int y = pix / 48, x = pix % 48;
#pragma unroll
    for (int i = 0; i < 3; ++i) {
#pragma unroll
        for (int j = 0; j < 3; ++j) {
            int u = i * 3 + j;
            int yq = y + 1 - i, xq = x + 1 - j;
            int so = -1;
            if (yq >= 0 && yq < 48 && xq >= 0 && xq < 48) {
                int m = idx[b * NPIX + yq * 48 + xq];
                int my = m / 48, mx = m % 48;
                int yy = my + i - 1, xx = mx + j - 1;
                if (yy >= 0 && yy < 48 && xx >= 0 && xx < 48) so = yy * 48 + xx;
            }
            soff[(b * 9 + u) * NPIX + pix] = so;
        }
    }
}

// ---------------- stage 3b: gather + fold via LDS-staged plane ----------------
#define CPB 4
__global__ __launch_bounds__(256) void k_out2(const float* __restrict__ x3,
                                              const int* __restrict__ soff,
                                              float* __restrict__ out) {
    __shared__ __align__(16) float plane[NPIX];
    const int t = threadIdx.x;
    const int img = blockIdx.x;
    const int b = img / 25, a = img % 25;

    int po[9][9];
#pragma unroll
    for (int u = 0; u < 9; ++u) {
        const int* sb = soff + (b * 9 + u) * NPIX;
#pragma unroll
        for (int k = 0; k < 9; ++k)
            po[k][u] = sb[k * 256 + t];
    }

    const size_t pbase = (size_t)b * 64 * 57600 + (size_t)a * 2304 +
                         (size_t)(blockIdx.y * CPB) * 57600;
    const float* gsrc = x3 + pbase;
    float* gdst = out + pbase;

    float4 r0, r1, r2;
    {
        const float4* g = (const float4*)gsrc;
        r0 = g[t]; r1 = g[t + 256];
        if (t < 64) r2 = g[t + 512];
    }
    float4* pl4 = (float4*)plane;
    pl4[t] = r0; pl4[t + 256] = r1;
    if (t < 64) pl4[t + 512] = r2;
    __syncthreads();

    for (int c = 0; c < CPB; ++c) {
        if (c + 1 < CPB) {
            const float4* g = (const float4*)(gsrc + (size_t)(c + 1) * 57600);
            r0 = g[t]; r1 = g[t + 256];
            if (t < 64) r2 = g[t + 512];
        }
        float* dst = gdst + (size_t)c * 57600;
#pragma unroll
        for (int k = 0; k < 9; ++k) {
            float acc = 0.f;
#pragma unroll
            for (int u = 0; u < 9; ++u) {
                int off = po[k][u];
                int ao = off < 0 ? 0 : off;
                float v = plane[ao];
                acc += (off < 0) ? 0.f : v;
            }
            dst[k * 256 + t] = acc;
        }
        __syncthreads();
        if (c + 1 < CPB) {
            pl4[t] = r0; pl4[t + 256] = r1;
            if (t < 64) pl4[t + 512] = r2;
        }
        __syncthreads();
    }
}

extern "C" void kernel_launch(void* const* d_in, const int* in_sizes, int n_in,
                              void* d_out, int out_size, void* d_ws, size_t ws_size,
                              hipStream_t stream) {
    const float* x1 = (const float*)d_in[0];
    const float* x2 = (const float*)d_in[1];
    const float* x3 = (const float*)d_in[2];
    const float* W  = (const float*)d_in[3];
    float* ws = (float*)d_ws;

    float* qp    = ws + OFF_QP;
    float* kp    = ws + OFF_KP;
    unsigned short* planes = (unsigned short*)(ws + OFF_PLANES);
    float* nk    = ws + OFF_NK;
    float* invNk = ws + OFF_INVNK;
    float* pval  = ws + OFF_PVAL;
    float* psec  = ws + OFF_PSEC;
    int*   pidx  = (int*)(ws + OFF_PIDX);
    int*   idx   = (int*)(ws + OFF_IDX);
    float* S     = ws + OFF_S;
    int*   soff  = (int*)(ws + OFF_SOFF);
    float* out   = (float*)d_out;

    const bool bigS = ws_size >= (size_t)(OFF_S + 2UL * (unsigned long)SSTRIDE) * 4UL;

    // zero qp/kp/planes (padding) — custom kernel, not latency-bound rocclr fill
    k_zero<<<2048, 256, 0, stream>>>((float4*)(ws + OFF_QP), (int)(OFF_NK / 4));

    k_qk<<<450, 256, 0, stream>>>(x1, x2, W, qp, kp, planes);
    k_nk<<<(2 * NPAD + 255) / 256, 256, 0, stream>>>(kp, nk);
    k_invnk<<<(2 * NPIX + 255) / 256, 256, 0, stream>>>(nk, invNk);

    if (bigS) {
        k_mfma2<<<dim3(20, 20, 2), 256, 0, stream>>>(planes, S, SSTRIDE, 0);
        k_argmax<<<dim3(48, 48, 2), 384, 0, stream>>>(S, invNk, pval, psec, pidx, SSTRIDE, 0);
        k_sel<<<dim3(576, 2), 256, 0, stream>>>(qp, kp, S, invNk, pval, psec, pidx,
                                                idx, SSTRIDE, 0);
    } else {
        for (int b = 0; b < 2; ++b) {
            k_mfma2<<<dim3(20, 20, 1), 256, 0, stream>>>(planes, S, 0L, b);
            k_argmax<<<dim3(48, 48, 1), 384, 0, stream>>>(S, invNk, pval, psec, pidx, 0L, b);
            k_sel<<<dim3(576, 1), 256, 0, stream>>>(qp, kp, S, invNk, pval, psec, pidx,
                                                    idx, 0L, b);
        }
    }
    k_soff<<<(2 * NPIX + 255) / 256, 256, 0, stream>>>(idx, soff);
    k_out2<<<dim3(50, 16), 256, 0, stream>>>(x3, soff, out);
}